// Round 1
// baseline (2500.338 us; speedup 1.0000x reference)
//
#include <hip/hip_runtime.h>
#include <cstdint>
#include <cstddef>

// Shapes are fixed by setup_inputs(): T=4096, D=2048, B=2, S=2048.
#define TT 4096
#define DD 2048
#define NH 16
#define HEADD 192
#define NOPE 128
#define VDIM 128
#define SEQ 2048

typedef __bf16 bf16x8 __attribute__((ext_vector_type(8)));
typedef float f32x4 __attribute__((ext_vector_type(4)));

__device__ __forceinline__ float bf2f(unsigned short u) {
    union { unsigned int i; float f; } v; v.i = ((unsigned int)u) << 16; return v.f;
}
__device__ __forceinline__ unsigned short f2bf(float f) {
    union { float f; unsigned int i; } v; v.f = f;
    unsigned int r = v.i + 0x7FFFu + ((v.i >> 16) & 1u);
    return (unsigned short)(r >> 16);
}

// ---------------- fp32 -> bf16 elementwise ----------------
__global__ __launch_bounds__(256) void cvt_bf16_k(const float* __restrict__ x,
                                                  unsigned short* __restrict__ y, int n) {
    int i = (blockIdx.x * 256 + threadIdx.x) * 4;
    if (i < n) {
        float4 v = *(const float4*)(x + i);
        uint2 o;
        o.x = (unsigned int)f2bf(v.x) | ((unsigned int)f2bf(v.y) << 16);
        o.y = (unsigned int)f2bf(v.z) | ((unsigned int)f2bf(v.w) << 16);
        *(uint2*)(y + i) = o;
    }
}

// ---------------- W[K,N] fp32 -> Wt[N,K] bf16 ----------------
__global__ __launch_bounds__(256) void transpose_cvt_k(const float* __restrict__ W,
                                                       unsigned short* __restrict__ Wt,
                                                       int K, int N) {
    __shared__ float tile[32][33];
    int n0 = blockIdx.x * 32, k0 = blockIdx.y * 32;
    int t = threadIdx.x, lr = t >> 5, lc = t & 31;
#pragma unroll
    for (int p = 0; p < 4; p++) {
        int k = k0 + lr + p * 8, n = n0 + lc;
        tile[lr + p * 8][lc] = (k < K && n < N) ? W[(size_t)k * N + n] : 0.f;
    }
    __syncthreads();
#pragma unroll
    for (int p = 0; p < 4; p++) {
        int n = n0 + lr + p * 8, k = k0 + lc;
        if (n < N && k < K) Wt[(size_t)n * K + k] = f2bf(tile[lc][lr + p * 8]);
    }
}

// ---------------- C[M,N] fp32 = A[M,K] bf16 @ Bt[N,K] bf16 ----------------
// 128x128 tile, BK=32, 256 thr = 4 waves (2x2), wave does 4x4 mfma_16x16x32 tiles.
// M must be multiple of 128, K multiple of 32; N arbitrary (guarded).
__global__ __launch_bounds__(256) void gemm_bf16_k(const unsigned short* __restrict__ A,
                                                   const unsigned short* __restrict__ Bt,
                                                   float* __restrict__ C,
                                                   int M, int N, int K) {
    __shared__ __align__(16) unsigned short As[128 * 32];
    __shared__ __align__(16) unsigned short Bs[128 * 32];
    int bm = blockIdx.y * 128, bn = blockIdx.x * 128;
    int t = threadIdx.x;
    int wave = t >> 6, lane = t & 63;
    int wr = (wave >> 1) * 64, wc = (wave & 1) * 64;
    int l15 = lane & 15, quad = lane >> 4;
    f32x4 acc[4][4];
    f32x4 zero = {0.f, 0.f, 0.f, 0.f};
#pragma unroll
    for (int i = 0; i < 4; i++)
#pragma unroll
        for (int j = 0; j < 4; j++) acc[i][j] = zero;
    int sr = t >> 1, sc = (t & 1) * 16;           // staging: thread loads 32B of row sr
    const unsigned short* pa = A + (size_t)(bm + sr) * K + sc;
    const unsigned short* pb = Bt + (size_t)(bn + sr) * K + sc;
    bool bok = (bn + sr) < N;
    for (int k0 = 0; k0 < K; k0 += 32) {
        uint4 a0 = *(const uint4*)(pa + k0);
        uint4 a1 = *(const uint4*)(pa + k0 + 8);
        uint4 b0, b1;
        if (bok) { b0 = *(const uint4*)(pb + k0); b1 = *(const uint4*)(pb + k0 + 8); }
        else     { b0.x = b0.y = b0.z = b0.w = 0u; b1 = b0; }
        *(uint4*)&As[sr * 32 + sc]     = a0;
        *(uint4*)&As[sr * 32 + sc + 8] = a1;
        *(uint4*)&Bs[sr * 32 + sc]     = b0;
        *(uint4*)&Bs[sr * 32 + sc + 8] = b1;
        __syncthreads();
        bf16x8 af[4], bfr[4];
#pragma unroll
        for (int i = 0; i < 4; i++)
            af[i] = *(const bf16x8*)&As[(wr + i * 16 + l15) * 32 + quad * 8];
#pragma unroll
        for (int j = 0; j < 4; j++)
            bfr[j] = *(const bf16x8*)&Bs[(wc + j * 16 + l15) * 32 + quad * 8];
#pragma unroll
        for (int i = 0; i < 4; i++)
#pragma unroll
            for (int j = 0; j < 4; j++)
                acc[i][j] = __builtin_amdgcn_mfma_f32_16x16x32_bf16(af[i], bfr[j], acc[i][j], 0, 0, 0);
        __syncthreads();
    }
    // C/D layout (m89/m91-verified): col = lane&15, row = (lane>>4)*4 + reg
#pragma unroll
    for (int i = 0; i < 4; i++) {
        int row = bm + wr + i * 16 + quad * 4;
#pragma unroll
        for (int j = 0; j < 4; j++) {
            int col = bn + wc + j * 16 + l15;
            if (col < N) {
                float* cp = C + (size_t)row * N + col;
#pragma unroll
                for (int r = 0; r < 4; r++) cp[(size_t)r * N] = acc[i][j][r];
            }
        }
    }
}

// ---------------- RMSNorm (block per row) ----------------
__global__ __launch_bounds__(256) void rmsnorm_k(const float* __restrict__ x,
                                                 const float* __restrict__ w,
                                                 unsigned short* __restrict__ y, int cols) {
    int row = blockIdx.x, t = threadIdx.x;
    const float* xr = x + (size_t)row * cols;
    float s = 0.f;
    for (int i = t; i < cols; i += 256) { float v = xr[i]; s += v * v; }
    __shared__ float red[256];
    red[t] = s; __syncthreads();
    for (int o = 128; o > 0; o >>= 1) { if (t < o) red[t] += red[t + o]; __syncthreads(); }
    float scale = rsqrtf(red[0] / (float)cols + 1e-6f);
    unsigned short* yr = y + (size_t)row * cols;
    for (int i = t; i < cols; i += 256) yr[i] = f2bf(xr[i] * scale * w[i]);
}

// ---------------- ckv[T,576] -> rmsnorm(512) bf16 + roped k_pe[64] bf16 ----------------
__global__ __launch_bounds__(256) void kvprep_k(const float* __restrict__ ckv,
                                                const float* __restrict__ w,
                                                const float* __restrict__ cosb,
                                                const float* __restrict__ sinb,
                                                unsigned short* __restrict__ ckvn,
                                                unsigned short* __restrict__ kpe) {
    int row = blockIdx.x, t = threadIdx.x;
    const float* xr = ckv + (size_t)row * 576;
    float s = 0.f;
#pragma unroll
    for (int i = t; i < 512; i += 256) { float v = xr[i]; s += v * v; }
    __shared__ float red[256];
    red[t] = s; __syncthreads();
    for (int o = 128; o > 0; o >>= 1) { if (t < o) red[t] += red[t + o]; __syncthreads(); }
    float scale = rsqrtf(red[0] / 512.f + 1e-6f);
    unsigned short* yr = ckvn + (size_t)row * 512;
#pragma unroll
    for (int i = t; i < 512; i += 256) yr[i] = f2bf(xr[i] * scale * w[i]);
    if (t < 32) {
        float e = xr[512 + 2 * t], o = xr[512 + 2 * t + 1];
        float c = cosb[row * 32 + t], sn = sinb[row * 32 + t];
        kpe[row * 64 + t]      = f2bf(e * c - o * sn);
        kpe[row * 64 + 32 + t] = f2bf(o * c + e * sn);
    }
}

// ---------------- q[T, H*192] fp32 -> Q bf16 with rope on dims 128..191 ----------------
__global__ __launch_bounds__(256) void qprep_k(const float* __restrict__ q,
                                               const float* __restrict__ cosb,
                                               const float* __restrict__ sinb,
                                               unsigned short* __restrict__ Qb) {
    int trow = blockIdx.x, t = threadIdx.x;
    const float* qr = q + (size_t)trow * (NH * HEADD);
    unsigned short* yr = Qb + (size_t)trow * (NH * HEADD);
    for (int i = t; i < NH * HEADD; i += 256) {
        int h = i / HEADD, d = i - h * HEADD;
        float val;
        if (d < NOPE) val = qr[i];
        else {
            int j = d - NOPE;
            int jj = j & 31;
            const float* pe = qr + h * HEADD + NOPE;
            float e = pe[2 * jj], o = pe[2 * jj + 1];
            float c = cosb[trow * 32 + jj], sn = sinb[trow * 32 + jj];
            val = (j < 32) ? (e * c - o * sn) : (o * c + e * sn);
        }
        yr[i] = f2bf(val);
    }
}

// ---------------- kvb[T,4096] fp32 -> K[T,H,192] bf16 (k_pe broadcast), V[T,H,128] bf16 --
__global__ __launch_bounds__(256) void kvprep2_k(const float* __restrict__ kvb,
                                                 const unsigned short* __restrict__ kpe,
                                                 unsigned short* __restrict__ Kb,
                                                 unsigned short* __restrict__ Vb) {
    int trow = blockIdx.x, t = threadIdx.x;
    const float* kr = kvb + (size_t)trow * 4096;
    unsigned short* kout = Kb + (size_t)trow * (NH * HEADD);
    unsigned short* vout = Vb + (size_t)trow * (NH * VDIM);
    for (int i = t; i < NH * HEADD; i += 256) {
        int h = i / HEADD, d = i - h * HEADD;
        kout[i] = (d < NOPE) ? f2bf(kr[h * 256 + d]) : kpe[trow * 64 + (d - NOPE)];
    }
    for (int i = t; i < NH * VDIM; i += 256) {
        int h = i / VDIM, d = i - h * VDIM;
        vout[i] = f2bf(kr[h * 256 + NOPE + d]);
    }
}

// ---------------- causal flash attention, fp32 vector ----------------
// block = (b,h,qt): 16 queries; iterate 32-key tiles with online softmax.
__global__ __launch_bounds__(256) void attn_k(const unsigned short* __restrict__ Qb,
                                              const unsigned short* __restrict__ Kb,
                                              const unsigned short* __restrict__ Vb,
                                              unsigned short* __restrict__ Oa) {
    const float SCALE = 0.07216878364870323f; // 192^-0.5
    int qt = blockIdx.x & 127;
    int h  = (blockIdx.x >> 7) & 15;
    int b  = blockIdx.x >> 11;
    int t  = threadIdx.x;
    __shared__ __align__(16) float Qs[16 * 196];
    __shared__ __align__(16) float Ks[32 * 196];
    __shared__ __align__(16) float Vs[32 * 128];
    __shared__ float Ps[16 * 33];
    __shared__ float rowm[16], rowl[16], rowa[16];
    int q0 = b * SEQ + qt * 16;
    // stage Q (16 x 192), bf16 -> fp32
    for (int c = t; c < 16 * 24; c += 256) {
        int r = c / 24, cc = (c % 24) * 8;
        uint4 u = *(const uint4*)(Qb + ((size_t)(q0 + r) * NH + h) * HEADD + cc);
        const unsigned short* sp = (const unsigned short*)&u;
        float* dst = Qs + r * 196 + cc;
#pragma unroll
        for (int j = 0; j < 8; j++) dst[j] = bf2f(sp[j]);
    }
    if (t < 16) { rowm[t] = -1e30f; rowl[t] = 0.f; }
    float Oacc[8];
#pragma unroll
    for (int j = 0; j < 8; j++) Oacc[j] = 0.f;
    int rs = t >> 4, cs = t & 15;   // score mapping: row rs, cols {cs, cs+16}
    int rp = t & 15, cg = t >> 4;   // PV mapping: row rp, col block cg*8
    int kt_max = (qt * 16 + 15) >> 5;
    for (int kt = 0; kt <= kt_max; kt++) {
        __syncthreads();
        int krow0 = b * SEQ + kt * 32;
        for (int c = t; c < 32 * 24; c += 256) {
            int rr = c / 24, cc = (c % 24) * 8;
            uint4 u = *(const uint4*)(Kb + ((size_t)(krow0 + rr) * NH + h) * HEADD + cc);
            const unsigned short* sp = (const unsigned short*)&u;
            float* dst = Ks + rr * 196 + cc;
#pragma unroll
            for (int j = 0; j < 8; j++) dst[j] = bf2f(sp[j]);
        }
        for (int c = t; c < 32 * 16; c += 256) {
            int rr = c / 16, cc = (c % 16) * 8;
            uint4 u = *(const uint4*)(Vb + ((size_t)(krow0 + rr) * NH + h) * VDIM + cc);
            const unsigned short* sp = (const unsigned short*)&u;
            float* dst = Vs + rr * 128 + cc;
#pragma unroll
            for (int j = 0; j < 8; j++) dst[j] = bf2f(sp[j]);
        }
        __syncthreads();
        // scores: 16x32 tile, 2 per thread
        float s0 = 0.f, s1 = 0.f;
        const float* qp  = Qs + rs * 196;
        const float* kp0 = Ks + cs * 196;
        const float* kp1 = Ks + (cs + 16) * 196;
#pragma unroll 8
        for (int d = 0; d < 192; d += 4) {
            float4 qv  = *(const float4*)(qp + d);
            float4 k0v = *(const float4*)(kp0 + d);
            float4 k1v = *(const float4*)(kp1 + d);
            s0 += qv.x * k0v.x + qv.y * k0v.y + qv.z * k0v.z + qv.w * k0v.w;
            s1 += qv.x * k1v.x + qv.y * k1v.y + qv.z * k1v.z + qv.w * k1v.w;
        }
        s0 *= SCALE; s1 *= SCALE;
        int qi = qt * 16 + rs;
        if (kt * 32 + cs > qi)      s0 = -1e30f;
        if (kt * 32 + cs + 16 > qi) s1 = -1e30f;
        Ps[rs * 33 + cs]      = s0;
        Ps[rs * 33 + cs + 16] = s1;
        __syncthreads();
        // online softmax stats (one thread per row)
        if (t < 16) {
            float* pr = Ps + t * 33;
            float m = rowm[t], nm = m;
            for (int c = 0; c < 32; c++) nm = fmaxf(nm, pr[c]);
            float a = __expf(m - nm);
            float sum = 0.f;
            for (int c = 0; c < 32; c++) { float e = __expf(pr[c] - nm); pr[c] = e; sum += e; }
            rowa[t] = a; rowm[t] = nm;
            rowl[t] = rowl[t] * a + sum;
        }
        __syncthreads();
        // rescale O and accumulate P@V
        float al = rowa[rp];
#pragma unroll
        for (int j = 0; j < 8; j++) Oacc[j] *= al;
        const float* pp = Ps + rp * 33;
        const float* vbase = Vs + cg * 8;
        for (int k = 0; k < 32; k++) {
            float p = pp[k];
            const float* vp = vbase + k * 128;
#pragma unroll
            for (int j = 0; j < 8; j++) Oacc[j] += p * vp[j];
        }
    }
    float inv = 1.f / rowl[rp];
    unsigned short* op = Oa + (size_t)(q0 + rp) * (NH * VDIM) + h * VDIM + cg * 8;
#pragma unroll
    for (int j = 0; j < 8; j++) op[j] = f2bf(Oacc[j] * inv);
}

// =====================================================================
extern "C" void kernel_launch(void* const* d_in, const int* in_sizes, int n_in,
                              void* d_out, int out_size, void* d_ws, size_t ws_size,
                              hipStream_t stream) {
    const float* hs     = (const float*)d_in[0];
    const float* cosb   = (const float*)d_in[1];
    const float* sinb   = (const float*)d_in[2];
    const float* w_q_a  = (const float*)d_in[3];
    const float* q_ln   = (const float*)d_in[4];
    const float* w_q_b  = (const float*)d_in[5];
    const float* w_kv_a = (const float*)d_in[6];
    const float* kv_ln  = (const float*)d_in[7];
    const float* w_kv_b = (const float*)d_in[8];
    const float* w_o    = (const float*)d_in[9];
    float* out = (float*)d_out;

    // workspace layout (~206 MiB total)
    char* base = (char*)d_ws;
    size_t off = 0;
    auto take = [&](size_t bytes) { void* p = base + off; off += (bytes + 255) & ~(size_t)255; return p; };
    unsigned short* wqaT  = (unsigned short*)take((size_t)1536 * 2048 * 2);
    unsigned short* wqbT  = (unsigned short*)take((size_t)3072 * 1536 * 2);
    unsigned short* wkvaT = (unsigned short*)take((size_t)576 * 2048 * 2);
    unsigned short* wkvbT = (unsigned short*)take((size_t)4096 * 512 * 2);
    unsigned short* woT   = (unsigned short*)take((size_t)2048 * 2048 * 2);
    unsigned short* hsb   = (unsigned short*)take((size_t)TT * DD * 2);
    unsigned short* qan   = (unsigned short*)take((size_t)TT * 1536 * 2);
    unsigned short* ckvn  = (unsigned short*)take((size_t)TT * 512 * 2);
    unsigned short* kpe   = (unsigned short*)take((size_t)TT * 64 * 2);
    unsigned short* Qbuf  = (unsigned short*)take((size_t)TT * NH * HEADD * 2);
    unsigned short* Kbuf  = (unsigned short*)take((size_t)TT * NH * HEADD * 2);
    unsigned short* Vbuf  = (unsigned short*)take((size_t)TT * NH * VDIM * 2);
    unsigned short* attnb = (unsigned short*)take((size_t)TT * 2048 * 2);
    float* S = (float*)take((size_t)TT * 4096 * 4);  // reused fp32 scratch (sequential lifetimes)

    // 0. activations + weights to bf16 (weights transposed to [N,K])
    cvt_bf16_k<<<(TT * DD) / 1024, 256, 0, stream>>>(hs, hsb, TT * DD);
    transpose_cvt_k<<<dim3(1536 / 32, 2048 / 32), 256, 0, stream>>>(w_q_a, wqaT, 2048, 1536);
    transpose_cvt_k<<<dim3(3072 / 32, 1536 / 32), 256, 0, stream>>>(w_q_b, wqbT, 1536, 3072);
    transpose_cvt_k<<<dim3(18, 2048 / 32), 256, 0, stream>>>(w_kv_a, wkvaT, 2048, 576);
    transpose_cvt_k<<<dim3(4096 / 32, 512 / 32), 256, 0, stream>>>(w_kv_b, wkvbT, 512, 4096);
    transpose_cvt_k<<<dim3(2048 / 32, 2048 / 32), 256, 0, stream>>>(w_o, woT, 2048, 2048);

    // 1. q_a = hs @ w_q_a ; rmsnorm -> qan (bf16)
    gemm_bf16_k<<<dim3(12, 32), 256, 0, stream>>>(hsb, wqaT, S, 4096, 1536, 2048);
    rmsnorm_k<<<4096, 256, 0, stream>>>(S, q_ln, qan, 1536);
    // 2. ckv = hs @ w_kv_a ; rmsnorm(512) + rope(k_pe)
    gemm_bf16_k<<<dim3(5, 32), 256, 0, stream>>>(hsb, wkvaT, S, 4096, 576, 2048);
    kvprep_k<<<4096, 256, 0, stream>>>(S, kv_ln, cosb, sinb, ckvn, kpe);
    // 3. q = qan @ w_q_b ; rope -> Qbuf
    gemm_bf16_k<<<dim3(24, 32), 256, 0, stream>>>(qan, wqbT, S, 4096, 3072, 1536);
    qprep_k<<<4096, 256, 0, stream>>>(S, cosb, sinb, Qbuf);
    // 4. kv = ckvn @ w_kv_b ; split K (with k_pe broadcast) / V
    gemm_bf16_k<<<dim3(32, 32), 256, 0, stream>>>(ckvn, wkvbT, S, 4096, 4096, 512);
    kvprep2_k<<<4096, 256, 0, stream>>>(S, kpe, Kbuf, Vbuf);
    // 5. attention
    attn_k<<<4096, 256, 0, stream>>>(Qbuf, Kbuf, Vbuf, attnb);
    // 6. out = attn @ w_o
    gemm_bf16_k<<<dim3(16, 32), 256, 0, stream>>>(attnb, woT, out, 4096, 2048, 2048);
}

// Round 2
// 817.987 us; speedup vs baseline: 3.0567x; 3.0567x over previous
//
#include <hip/hip_runtime.h>
#include <cstdint>
#include <cstddef>

// Shapes are fixed by setup_inputs(): T=4096, D=2048, B=2, S=2048.
#define TT 4096
#define DD 2048
#define NH 16
#define HEADD 192
#define NOPE 128
#define VDIM 128
#define SEQ 2048

typedef __bf16 bf16x8 __attribute__((ext_vector_type(8)));
typedef float f32x4 __attribute__((ext_vector_type(4)));

__device__ __forceinline__ float bf2f(unsigned short u) {
    union { unsigned int i; float f; } v; v.i = ((unsigned int)u) << 16; return v.f;
}
__device__ __forceinline__ unsigned short f2bf(float f) {
    union { float f; unsigned int i; } v; v.f = f;
    unsigned int r = v.i + 0x7FFFu + ((v.i >> 16) & 1u);
    return (unsigned short)(r >> 16);
}

// ---------------- fp32 -> bf16 elementwise ----------------
__global__ __launch_bounds__(256) void cvt_bf16_k(const float* __restrict__ x,
                                                  unsigned short* __restrict__ y, int n) {
    int i = (blockIdx.x * 256 + threadIdx.x) * 4;
    if (i < n) {
        float4 v = *(const float4*)(x + i);
        uint2 o;
        o.x = (unsigned int)f2bf(v.x) | ((unsigned int)f2bf(v.y) << 16);
        o.y = (unsigned int)f2bf(v.z) | ((unsigned int)f2bf(v.w) << 16);
        *(uint2*)(y + i) = o;
    }
}

// ---------------- W[K,N] fp32 -> Wt[N,K] bf16 ----------------
__global__ __launch_bounds__(256) void transpose_cvt_k(const float* __restrict__ W,
                                                       unsigned short* __restrict__ Wt,
                                                       int K, int N) {
    __shared__ float tile[32][33];
    int n0 = blockIdx.x * 32, k0 = blockIdx.y * 32;
    int t = threadIdx.x, lr = t >> 5, lc = t & 31;
#pragma unroll
    for (int p = 0; p < 4; p++) {
        int k = k0 + lr + p * 8, n = n0 + lc;
        tile[lr + p * 8][lc] = (k < K && n < N) ? W[(size_t)k * N + n] : 0.f;
    }
    __syncthreads();
#pragma unroll
    for (int p = 0; p < 4; p++) {
        int n = n0 + lr + p * 8, k = k0 + lc;
        if (n < N && k < K) Wt[(size_t)n * K + k] = f2bf(tile[lc][lr + p * 8]);
    }
}

// ---------------- C[M,N] fp32 = A[M,K] bf16 @ Bt[N,K] bf16 ----------------
__global__ __launch_bounds__(256) void gemm_bf16_k(const unsigned short* __restrict__ A,
                                                   const unsigned short* __restrict__ Bt,
                                                   float* __restrict__ C,
                                                   int M, int N, int K) {
    __shared__ __align__(16) unsigned short As[128 * 32];
    __shared__ __align__(16) unsigned short Bs[128 * 32];
    int bm = blockIdx.y * 128, bn = blockIdx.x * 128;
    int t = threadIdx.x;
    int wave = t >> 6, lane = t & 63;
    int wr = (wave >> 1) * 64, wc = (wave & 1) * 64;
    int l15 = lane & 15, quad = lane >> 4;
    f32x4 acc[4][4];
    f32x4 zero = {0.f, 0.f, 0.f, 0.f};
#pragma unroll
    for (int i = 0; i < 4; i++)
#pragma unroll
        for (int j = 0; j < 4; j++) acc[i][j] = zero;
    int sr = t >> 1, sc = (t & 1) * 16;
    const unsigned short* pa = A + (size_t)(bm + sr) * K + sc;
    const unsigned short* pb = Bt + (size_t)(bn + sr) * K + sc;
    bool bok = (bn + sr) < N;
    for (int k0 = 0; k0 < K; k0 += 32) {
        uint4 a0 = *(const uint4*)(pa + k0);
        uint4 a1 = *(const uint4*)(pa + k0 + 8);
        uint4 b0, b1;
        if (bok) { b0 = *(const uint4*)(pb + k0); b1 = *(const uint4*)(pb + k0 + 8); }
        else     { b0.x = b0.y = b0.z = b0.w = 0u; b1 = b0; }
        *(uint4*)&As[sr * 32 + sc]     = a0;
        *(uint4*)&As[sr * 32 + sc + 8] = a1;
        *(uint4*)&Bs[sr * 32 + sc]     = b0;
        *(uint4*)&Bs[sr * 32 + sc + 8] = b1;
        __syncthreads();
        bf16x8 af[4], bfr[4];
#pragma unroll
        for (int i = 0; i < 4; i++)
            af[i] = *(const bf16x8*)&As[(wr + i * 16 + l15) * 32 + quad * 8];
#pragma unroll
        for (int j = 0; j < 4; j++)
            bfr[j] = *(const bf16x8*)&Bs[(wc + j * 16 + l15) * 32 + quad * 8];
#pragma unroll
        for (int i = 0; i < 4; i++)
#pragma unroll
            for (int j = 0; j < 4; j++)
                acc[i][j] = __builtin_amdgcn_mfma_f32_16x16x32_bf16(af[i], bfr[j], acc[i][j], 0, 0, 0);
        __syncthreads();
    }
#pragma unroll
    for (int i = 0; i < 4; i++) {
        int row = bm + wr + i * 16 + quad * 4;
#pragma unroll
        for (int j = 0; j < 4; j++) {
            int col = bn + wc + j * 16 + l15;
            if (col < N) {
                float* cp = C + (size_t)row * N + col;
#pragma unroll
                for (int r = 0; r < 4; r++) cp[(size_t)r * N] = acc[i][j][r];
            }
        }
    }
}

// ---------------- RMSNorm (block per row) ----------------
__global__ __launch_bounds__(256) void rmsnorm_k(const float* __restrict__ x,
                                                 const float* __restrict__ w,
                                                 unsigned short* __restrict__ y, int cols) {
    int row = blockIdx.x, t = threadIdx.x;
    const float* xr = x + (size_t)row * cols;
    float s = 0.f;
    for (int i = t; i < cols; i += 256) { float v = xr[i]; s += v * v; }
    __shared__ float red[256];
    red[t] = s; __syncthreads();
    for (int o = 128; o > 0; o >>= 1) { if (t < o) red[t] += red[t + o]; __syncthreads(); }
    float scale = rsqrtf(red[0] / (float)cols + 1e-6f);
    unsigned short* yr = y + (size_t)row * cols;
    for (int i = t; i < cols; i += 256) yr[i] = f2bf(xr[i] * scale * w[i]);
}

// ---------------- ckv[T,576] -> rmsnorm(512) bf16 + roped k_pe[64] bf16 ----------------
__global__ __launch_bounds__(256) void kvprep_k(const float* __restrict__ ckv,
                                                const float* __restrict__ w,
                                                const float* __restrict__ cosb,
                                                const float* __restrict__ sinb,
                                                unsigned short* __restrict__ ckvn,
                                                unsigned short* __restrict__ kpe) {
    int row = blockIdx.x, t = threadIdx.x;
    const float* xr = ckv + (size_t)row * 576;
    float s = 0.f;
#pragma unroll
    for (int i = t; i < 512; i += 256) { float v = xr[i]; s += v * v; }
    __shared__ float red[256];
    red[t] = s; __syncthreads();
    for (int o = 128; o > 0; o >>= 1) { if (t < o) red[t] += red[t + o]; __syncthreads(); }
    float scale = rsqrtf(red[0] / 512.f + 1e-6f);
    unsigned short* yr = ckvn + (size_t)row * 512;
#pragma unroll
    for (int i = t; i < 512; i += 256) yr[i] = f2bf(xr[i] * scale * w[i]);
    if (t < 32) {
        float e = xr[512 + 2 * t], o = xr[512 + 2 * t + 1];
        float c = cosb[row * 32 + t], sn = sinb[row * 32 + t];
        kpe[row * 64 + t]      = f2bf(e * c - o * sn);
        kpe[row * 64 + 32 + t] = f2bf(o * c + e * sn);
    }
}

// ---------------- q[T, H*192] fp32 -> Q bf16 with rope on dims 128..191 ----------------
__global__ __launch_bounds__(256) void qprep_k(const float* __restrict__ q,
                                               const float* __restrict__ cosb,
                                               const float* __restrict__ sinb,
                                               unsigned short* __restrict__ Qb) {
    int trow = blockIdx.x, t = threadIdx.x;
    const float* qr = q + (size_t)trow * (NH * HEADD);
    unsigned short* yr = Qb + (size_t)trow * (NH * HEADD);
    for (int i = t; i < NH * HEADD; i += 256) {
        int h = i / HEADD, d = i - h * HEADD;
        float val;
        if (d < NOPE) val = qr[i];
        else {
            int j = d - NOPE;
            int jj = j & 31;
            const float* pe = qr + h * HEADD + NOPE;
            float e = pe[2 * jj], o = pe[2 * jj + 1];
            float c = cosb[trow * 32 + jj], sn = sinb[trow * 32 + jj];
            val = (j < 32) ? (e * c - o * sn) : (o * c + e * sn);
        }
        yr[i] = f2bf(val);
    }
}

// ---------------- kvb[T,4096] fp32 -> K[T,H,192] bf16 (k_pe broadcast) ----------------
__global__ __launch_bounds__(256) void kprep_k(const float* __restrict__ kvb,
                                               const unsigned short* __restrict__ kpe,
                                               unsigned short* __restrict__ Kb) {
    int trow = blockIdx.x, t = threadIdx.x;
    const float* kr = kvb + (size_t)trow * 4096;
    unsigned short* kout = Kb + (size_t)trow * (NH * HEADD);
    for (int i = t; i < NH * HEADD; i += 256) {
        int h = i / HEADD, d = i - h * HEADD;
        kout[i] = (d < NOPE) ? f2bf(kr[h * 256 + d]) : kpe[trow * 64 + (d - NOPE)];
    }
}

// ---------------- kvb[T,4096] fp32 -> Vt[b*H+h][128][2048] bf16 (transposed) ----------
// block = (seq-tile 64, h, b). LDS tile transpose, coalesced both ways.
__global__ __launch_bounds__(256) void vtrans_k(const float* __restrict__ kvb,
                                                unsigned short* __restrict__ Vtg) {
    __shared__ unsigned short tile[64][132];
    int st = blockIdx.x, h = blockIdx.y, b = blockIdx.z;
    int t = threadIdx.x;
    int s0 = b * SEQ + st * 64;
    // load: 64 seq rows x 128 dims (float4 = 4 dims), convert to bf16
    for (int c = t; c < 64 * 32; c += 256) {
        int r = c >> 5, d4 = (c & 31) * 4;
        float4 v = *(const float4*)(kvb + (size_t)(s0 + r) * 4096 + h * 256 + NOPE + d4);
        tile[r][d4]     = f2bf(v.x);
        tile[r][d4 + 1] = f2bf(v.y);
        tile[r][d4 + 2] = f2bf(v.z);
        tile[r][d4 + 3] = f2bf(v.w);
    }
    __syncthreads();
    // store: 128 dim rows x 64 seq (uint2 = 4 keys)
    int bh = b * NH + h;
    for (int c = t; c < 128 * 16; c += 256) {
        int d = c >> 4, s4 = (c & 15) * 4;
        unsigned short p0 = tile[s4][d], p1 = tile[s4 + 1][d];
        unsigned short p2 = tile[s4 + 2][d], p3 = tile[s4 + 3][d];
        uint2 o;
        o.x = (unsigned int)p0 | ((unsigned int)p1 << 16);
        o.y = (unsigned int)p2 | ((unsigned int)p3 << 16);
        *(uint2*)(Vtg + ((size_t)bh * VDIM + d) * SEQ + st * 64 + s4) = o;
    }
}

// ---------------- causal flash attention, MFMA bf16 ----------------
// block = (qt, h, b): 64 queries, 4 waves x 16 Q-rows; K-tiles of 64 keys.
#define KS_STRIDE 200
#define VT_STRIDE 72
#define P_STRIDE  72
__global__ __launch_bounds__(256) void attn_mfma_k(const unsigned short* __restrict__ Qb,
                                                   const unsigned short* __restrict__ Kb,
                                                   const unsigned short* __restrict__ Vtg,
                                                   unsigned short* __restrict__ Oa) {
    const float SCALE = 0.07216878364870323f; // 192^-0.5
    __shared__ __align__(16) unsigned short Ks[64 * KS_STRIDE];
    __shared__ __align__(16) unsigned short Vts[128 * VT_STRIDE];
    __shared__ __align__(16) unsigned short Pw[4 * 16 * P_STRIDE];
    int qt = gridDim.x - 1 - blockIdx.x;   // descending: long blocks first
    int h  = blockIdx.y;
    int b  = blockIdx.z;
    int t  = threadIdx.x;
    int w = t >> 6, lane = t & 63;
    int l15 = lane & 15, quad = lane >> 4;
    int bh = b * NH + h;
    int q0 = b * SEQ + qt * 64;            // global row of block's first query
    int qloc = qt * 64 + w * 16 + quad * 4; // local (in-seq) base row of lane's rows

    // preload Q fragments: wave w owns Q rows q0 + w*16 + (0..15)
    bf16x8 qf[6];
    {
        const unsigned short* qbase = Qb + ((size_t)(q0 + w * 16 + l15) * NH + h) * HEADD + quad * 8;
#pragma unroll
        for (int c = 0; c < 6; c++)
            qf[c] = *(const bf16x8*)(qbase + c * 32);
    }
    f32x4 acc_o[8];
    f32x4 zero = {0.f, 0.f, 0.f, 0.f};
#pragma unroll
    for (int j = 0; j < 8; j++) acc_o[j] = zero;
    float mrun[4], lrun[4];
#pragma unroll
    for (int r = 0; r < 4; r++) { mrun[r] = -1e30f; lrun[r] = 0.f; }

    unsigned short* Pme = Pw + w * 16 * P_STRIDE;
    for (int kt = 0; kt <= qt; kt++) {
        __syncthreads();   // previous iteration done with Ks/Vts
        int k0 = b * SEQ + kt * 64;
        // stage K tile: 64 keys x 192 dims
        for (int c = t; c < 64 * 24; c += 256) {
            int r = c / 24, cc = (c % 24) * 8;
            uint4 u = *(const uint4*)(Kb + ((size_t)(k0 + r) * NH + h) * HEADD + cc);
            *(uint4*)&Ks[r * KS_STRIDE + cc] = u;
        }
        // stage Vt tile: 128 dims x 64 keys (already transposed in global)
        for (int c = t; c < 128 * 8; c += 256) {
            int d = c >> 3, cc = (c & 7) * 8;
            uint4 u = *(const uint4*)(Vtg + ((size_t)bh * VDIM + d) * SEQ + kt * 64 + cc);
            *(uint4*)&Vts[d * VT_STRIDE + cc] = u;
        }
        __syncthreads();
        // S = Q K^T  : 4 col-tiles x 6 k-chunks
        f32x4 acc_s[4];
#pragma unroll
        for (int j = 0; j < 4; j++) acc_s[j] = zero;
#pragma unroll
        for (int c = 0; c < 6; c++) {
#pragma unroll
            for (int j = 0; j < 4; j++) {
                bf16x8 kf = *(const bf16x8*)&Ks[(j * 16 + l15) * KS_STRIDE + c * 32 + quad * 8];
                acc_s[j] = __builtin_amdgcn_mfma_f32_16x16x32_bf16(qf[c], kf, acc_s[j], 0, 0, 0);
            }
        }
        // mask + scale; online softmax. Lane holds rows qloc+(0..3) (reg), cols kt*64 + j*16 + l15.
        float sv[4][4];
#pragma unroll
        for (int j = 0; j < 4; j++) {
            int kcol = kt * 64 + j * 16 + l15;
#pragma unroll
            for (int r = 0; r < 4; r++)
                sv[j][r] = (kcol > qloc + r) ? -1e30f : acc_s[j][r] * SCALE;
        }
        float alpha[4];
#pragma unroll
        for (int r = 0; r < 4; r++) {
            float v = fmaxf(fmaxf(sv[0][r], sv[1][r]), fmaxf(sv[2][r], sv[3][r]));
            v = fmaxf(v, __shfl_xor(v, 1));
            v = fmaxf(v, __shfl_xor(v, 2));
            v = fmaxf(v, __shfl_xor(v, 4));
            v = fmaxf(v, __shfl_xor(v, 8));
            float mnew = fmaxf(mrun[r], v);
            alpha[r] = __expf(mrun[r] - mnew);
            mrun[r] = mnew;
            float rs = 0.f;
#pragma unroll
            for (int j = 0; j < 4; j++) { float p = __expf(sv[j][r] - mnew); sv[j][r] = p; rs += p; }
            rs += __shfl_xor(rs, 1);
            rs += __shfl_xor(rs, 2);
            rs += __shfl_xor(rs, 4);
            rs += __shfl_xor(rs, 8);
            lrun[r] = lrun[r] * alpha[r] + rs;
        }
        // write P (bf16) to per-wave LDS in [row][key] layout
#pragma unroll
        for (int j = 0; j < 4; j++)
#pragma unroll
            for (int r = 0; r < 4; r++)
                Pme[(quad * 4 + r) * P_STRIDE + j * 16 + l15] = f2bf(sv[j][r]);
        // rescale O
#pragma unroll
        for (int jt = 0; jt < 8; jt++)
#pragma unroll
            for (int r = 0; r < 4; r++) acc_o[jt][r] *= alpha[r];
        __syncthreads();   // P visible wave-wide (and cheap block-wide)
        // O += P @ V : 8 dim-tiles x 2 k-chunks
#pragma unroll
        for (int c2 = 0; c2 < 2; c2++) {
            bf16x8 pf = *(const bf16x8*)&Pme[l15 * P_STRIDE + c2 * 32 + quad * 8];
#pragma unroll
            for (int jt = 0; jt < 8; jt++) {
                bf16x8 vf = *(const bf16x8*)&Vts[(jt * 16 + l15) * VT_STRIDE + c2 * 32 + quad * 8];
                acc_o[jt] = __builtin_amdgcn_mfma_f32_16x16x32_bf16(pf, vf, acc_o[jt], 0, 0, 0);
            }
        }
    }
    // epilogue: normalize, store bf16 to attnb[T][H*128]
    float inv[4];
#pragma unroll
    for (int r = 0; r < 4; r++) inv[r] = 1.f / lrun[r];
#pragma unroll
    for (int r = 0; r < 4; r++) {
        unsigned short* op = Oa + (size_t)(q0 + w * 16 + quad * 4 + r) * (NH * VDIM) + h * VDIM + l15;
#pragma unroll
        for (int jt = 0; jt < 8; jt++)
            op[jt * 16] = f2bf(acc_o[jt][r] * inv[r]);
    }
}

// =====================================================================
extern "C" void kernel_launch(void* const* d_in, const int* in_sizes, int n_in,
                              void* d_out, int out_size, void* d_ws, size_t ws_size,
                              hipStream_t stream) {
    const float* hs     = (const float*)d_in[0];
    const float* cosb   = (const float*)d_in[1];
    const float* sinb   = (const float*)d_in[2];
    const float* w_q_a  = (const float*)d_in[3];
    const float* q_ln   = (const float*)d_in[4];
    const float* w_q_b  = (const float*)d_in[5];
    const float* w_kv_a = (const float*)d_in[6];
    const float* kv_ln  = (const float*)d_in[7];
    const float* w_kv_b = (const float*)d_in[8];
    const float* w_o    = (const float*)d_in[9];
    float* out = (float*)d_out;

    char* base = (char*)d_ws;
    size_t off = 0;
    auto take = [&](size_t bytes) { void* p = base + off; off += (bytes + 255) & ~(size_t)255; return p; };
    unsigned short* wqaT  = (unsigned short*)take((size_t)1536 * 2048 * 2);
    unsigned short* wqbT  = (unsigned short*)take((size_t)3072 * 1536 * 2);
    unsigned short* wkvaT = (unsigned short*)take((size_t)576 * 2048 * 2);
    unsigned short* wkvbT = (unsigned short*)take((size_t)4096 * 512 * 2);
    unsigned short* woT   = (unsigned short*)take((size_t)2048 * 2048 * 2);
    unsigned short* hsb   = (unsigned short*)take((size_t)TT * DD * 2);
    unsigned short* qan   = (unsigned short*)take((size_t)TT * 1536 * 2);
    unsigned short* ckvn  = (unsigned short*)take((size_t)TT * 512 * 2);
    unsigned short* kpe   = (unsigned short*)take((size_t)TT * 64 * 2);
    unsigned short* Qbuf  = (unsigned short*)take((size_t)TT * NH * HEADD * 2);
    unsigned short* Kbuf  = (unsigned short*)take((size_t)TT * NH * HEADD * 2);
    unsigned short* Vtg   = (unsigned short*)take((size_t)TT * NH * VDIM * 2);  // [b*H+h][128][2048]
    unsigned short* attnb = (unsigned short*)take((size_t)TT * 2048 * 2);
    float* S = (float*)take((size_t)TT * 4096 * 4);  // reused fp32 scratch

    // 0. activations + weights to bf16 (weights transposed to [N,K])
    cvt_bf16_k<<<(TT * DD) / 1024, 256, 0, stream>>>(hs, hsb, TT * DD);
    transpose_cvt_k<<<dim3(1536 / 32, 2048 / 32), 256, 0, stream>>>(w_q_a, wqaT, 2048, 1536);
    transpose_cvt_k<<<dim3(3072 / 32, 1536 / 32), 256, 0, stream>>>(w_q_b, wqbT, 1536, 3072);
    transpose_cvt_k<<<dim3(18, 2048 / 32), 256, 0, stream>>>(w_kv_a, wkvaT, 2048, 576);
    transpose_cvt_k<<<dim3(4096 / 32, 512 / 32), 256, 0, stream>>>(w_kv_b, wkvbT, 512, 4096);
    transpose_cvt_k<<<dim3(2048 / 32, 2048 / 32), 256, 0, stream>>>(w_o, woT, 2048, 2048);

    // 1. q_a = hs @ w_q_a ; rmsnorm -> qan (bf16)
    gemm_bf16_k<<<dim3(12, 32), 256, 0, stream>>>(hsb, wqaT, S, 4096, 1536, 2048);
    rmsnorm_k<<<4096, 256, 0, stream>>>(S, q_ln, qan, 1536);
    // 2. ckv = hs @ w_kv_a ; rmsnorm(512) + rope(k_pe)
    gemm_bf16_k<<<dim3(5, 32), 256, 0, stream>>>(hsb, wkvaT, S, 4096, 576, 2048);
    kvprep_k<<<4096, 256, 0, stream>>>(S, kv_ln, cosb, sinb, ckvn, kpe);
    // 3. q = qan @ w_q_b ; rope -> Qbuf
    gemm_bf16_k<<<dim3(24, 32), 256, 0, stream>>>(qan, wqbT, S, 4096, 3072, 1536);
    qprep_k<<<4096, 256, 0, stream>>>(S, cosb, sinb, Qbuf);
    // 4. kv = ckvn @ w_kv_b ; K (with k_pe broadcast), V transposed to [bh][d][s]
    gemm_bf16_k<<<dim3(32, 32), 256, 0, stream>>>(ckvn, wkvbT, S, 4096, 4096, 512);
    kprep_k<<<4096, 256, 0, stream>>>(S, kpe, Kbuf);
    vtrans_k<<<dim3(32, 16, 2), 256, 0, stream>>>(S, Vtg);
    // 5. attention (MFMA flash)
    attn_mfma_k<<<dim3(32, 16, 2), 256, 0, stream>>>(Qbuf, Kbuf, Vtg, attnb);
    // 6. out = attn @ w_o
    gemm_bf16_k<<<dim3(16, 32), 256, 0, stream>>>(attnb, woT, out, 4096, 2048, 2048);
}

// Round 3
// 757.037 us; speedup vs baseline: 3.3028x; 1.0805x over previous
//
#include <hip/hip_runtime.h>
#include <cstdint>
#include <cstddef>

// Shapes are fixed by setup_inputs(): T=4096, D=2048, B=2, S=2048.
#define TT 4096
#define DD 2048
#define NH 16
#define HEADD 192
#define NOPE 128
#define VDIM 128
#define SEQ 2048

typedef __bf16 bf16x8 __attribute__((ext_vector_type(8)));
typedef float f32x4 __attribute__((ext_vector_type(4)));
typedef unsigned int u32;

__device__ __forceinline__ float bf2f(unsigned short u) {
    union { unsigned int i; float f; } v; v.i = ((unsigned int)u) << 16; return v.f;
}
__device__ __forceinline__ unsigned short f2bf(float f) {
    union { float f; unsigned int i; } v; v.f = f;
    unsigned int r = v.i + 0x7FFFu + ((v.i >> 16) & 1u);
    return (unsigned short)(r >> 16);
}
// async global->LDS, 16B per lane; LDS dest = wave-uniform base + lane*16
__device__ __forceinline__ void gload16(const unsigned short* g, unsigned short* l) {
    __builtin_amdgcn_global_load_lds((const __attribute__((address_space(1))) u32*)g,
                                     (__attribute__((address_space(3))) u32*)l, 16, 0, 0);
}

// ---------------- fp32 -> bf16 elementwise ----------------
__global__ __launch_bounds__(256) void cvt_bf16_k(const float* __restrict__ x,
                                                  unsigned short* __restrict__ y, int n) {
    int i = (blockIdx.x * 256 + threadIdx.x) * 4;
    if (i < n) {
        float4 v = *(const float4*)(x + i);
        uint2 o;
        o.x = (unsigned int)f2bf(v.x) | ((unsigned int)f2bf(v.y) << 16);
        o.y = (unsigned int)f2bf(v.z) | ((unsigned int)f2bf(v.w) << 16);
        *(uint2*)(y + i) = o;
    }
}

// ---------------- W[K,N] fp32 -> Wt[N,K] bf16 ----------------
__global__ __launch_bounds__(256) void transpose_cvt_k(const float* __restrict__ W,
                                                       unsigned short* __restrict__ Wt,
                                                       int K, int N) {
    __shared__ float tile[32][33];
    int n0 = blockIdx.x * 32, k0 = blockIdx.y * 32;
    int t = threadIdx.x, lr = t >> 5, lc = t & 31;
#pragma unroll
    for (int p = 0; p < 4; p++) {
        int k = k0 + lr + p * 8, n = n0 + lc;
        tile[lr + p * 8][lc] = (k < K && n < N) ? W[(size_t)k * N + n] : 0.f;
    }
    __syncthreads();
#pragma unroll
    for (int p = 0; p < 4; p++) {
        int n = n0 + lr + p * 8, k = k0 + lc;
        if (n < N && k < K) Wt[(size_t)n * K + k] = f2bf(tile[lc][lr + p * 8]);
    }
}

// ---------------- C[M,N] fp32 = A[M,K] bf16 @ Bt[N,K] bf16 ----------------
// 128x128 tile, BK=32, async global_load_lds staging (m97 pattern).
__global__ __launch_bounds__(256) void gemm_bf16_k(const unsigned short* __restrict__ A,
                                                   const unsigned short* __restrict__ Bt,
                                                   float* __restrict__ C,
                                                   int M, int N, int K) {
    __shared__ __align__(16) unsigned short As[128 * 32];
    __shared__ __align__(16) unsigned short Bs[128 * 32];
    int bm = blockIdx.y * 128, bn = blockIdx.x * 128;
    int t = threadIdx.x;
    int wave = t >> 6, lane = t & 63;
    int wr = (wave >> 1) * 64, wc = (wave & 1) * 64;
    int l15 = lane & 15, quad = lane >> 4;
    f32x4 acc[4][4];
    f32x4 zero = {0.f, 0.f, 0.f, 0.f};
#pragma unroll
    for (int i = 0; i < 4; i++)
#pragma unroll
        for (int j = 0; j < 4; j++) acc[i][j] = zero;
    // async staging: wave w stages 1KB chunks {2w, 2w+1} of both As and Bs.
    // chunk i covers tile rows 16i..16i+15 (64B per row); lane l -> row 16i + l/4, bytes (l&3)*16.
    int r0 = 16 * (2 * wave) + (lane >> 2);
    int cOff = (lane & 3) * 8;   // shorts
    const unsigned short* gA0 = A + (size_t)(bm + r0) * K + cOff;
    const unsigned short* gA1 = A + (size_t)(bm + r0 + 16) * K + cOff;
    const unsigned short* gB0 = Bt + (size_t)(bn + r0) * K + cOff;
    const unsigned short* gB1 = Bt + (size_t)(bn + r0 + 16) * K + cOff;
    unsigned short* lA0 = &As[(2 * wave) * 512];
    unsigned short* lA1 = &As[(2 * wave + 1) * 512];
    unsigned short* lB0 = &Bs[(2 * wave) * 512];
    unsigned short* lB1 = &Bs[(2 * wave + 1) * 512];
    for (int k0 = 0; k0 < K; k0 += 32) {
        gload16(gA0 + k0, lA0);
        gload16(gA1 + k0, lA1);
        gload16(gB0 + k0, lB0);
        gload16(gB1 + k0, lB1);
        __syncthreads();   // drains vmcnt: async loads landed
        bf16x8 af[4], bfr[4];
#pragma unroll
        for (int i = 0; i < 4; i++)
            af[i] = *(const bf16x8*)&As[(wr + i * 16 + l15) * 32 + quad * 8];
#pragma unroll
        for (int j = 0; j < 4; j++)
            bfr[j] = *(const bf16x8*)&Bs[(wc + j * 16 + l15) * 32 + quad * 8];
#pragma unroll
        for (int i = 0; i < 4; i++)
#pragma unroll
            for (int j = 0; j < 4; j++)
                acc[i][j] = __builtin_amdgcn_mfma_f32_16x16x32_bf16(af[i], bfr[j], acc[i][j], 0, 0, 0);
        __syncthreads();
    }
#pragma unroll
    for (int i = 0; i < 4; i++) {
        int row = bm + wr + i * 16 + quad * 4;
#pragma unroll
        for (int j = 0; j < 4; j++) {
            int col = bn + wc + j * 16 + l15;
            if (col < N) {
                float* cp = C + (size_t)row * N + col;
#pragma unroll
                for (int r = 0; r < 4; r++) cp[(size_t)r * N] = acc[i][j][r];
            }
        }
    }
}

// ---------------- RMSNorm (block per row) ----------------
__global__ __launch_bounds__(256) void rmsnorm_k(const float* __restrict__ x,
                                                 const float* __restrict__ w,
                                                 unsigned short* __restrict__ y, int cols) {
    int row = blockIdx.x, t = threadIdx.x;
    const float* xr = x + (size_t)row * cols;
    float s = 0.f;
    for (int i = t; i < cols; i += 256) { float v = xr[i]; s += v * v; }
    __shared__ float red[256];
    red[t] = s; __syncthreads();
    for (int o = 128; o > 0; o >>= 1) { if (t < o) red[t] += red[t + o]; __syncthreads(); }
    float scale = rsqrtf(red[0] / (float)cols + 1e-6f);
    unsigned short* yr = y + (size_t)row * cols;
    for (int i = t; i < cols; i += 256) yr[i] = f2bf(xr[i] * scale * w[i]);
}

// ---------------- ckv[T,576] -> rmsnorm(512) bf16 + roped k_pe[64] bf16 ----------------
__global__ __launch_bounds__(256) void kvprep_k(const float* __restrict__ ckv,
                                                const float* __restrict__ w,
                                                const float* __restrict__ cosb,
                                                const float* __restrict__ sinb,
                                                unsigned short* __restrict__ ckvn,
                                                unsigned short* __restrict__ kpe) {
    int row = blockIdx.x, t = threadIdx.x;
    const float* xr = ckv + (size_t)row * 576;
    float s = 0.f;
#pragma unroll
    for (int i = t; i < 512; i += 256) { float v = xr[i]; s += v * v; }
    __shared__ float red[256];
    red[t] = s; __syncthreads();
    for (int o = 128; o > 0; o >>= 1) { if (t < o) red[t] += red[t + o]; __syncthreads(); }
    float scale = rsqrtf(red[0] / 512.f + 1e-6f);
    unsigned short* yr = ckvn + (size_t)row * 512;
#pragma unroll
    for (int i = t; i < 512; i += 256) yr[i] = f2bf(xr[i] * scale * w[i]);
    if (t < 32) {
        float e = xr[512 + 2 * t], o = xr[512 + 2 * t + 1];
        float c = cosb[row * 32 + t], sn = sinb[row * 32 + t];
        kpe[row * 64 + t]      = f2bf(e * c - o * sn);
        kpe[row * 64 + 32 + t] = f2bf(o * c + e * sn);
    }
}

// ---------------- q[T, H*192] fp32 -> Q bf16 with rope on dims 128..191 ----------------
__global__ __launch_bounds__(256) void qprep_k(const float* __restrict__ q,
                                               const float* __restrict__ cosb,
                                               const float* __restrict__ sinb,
                                               unsigned short* __restrict__ Qb) {
    int trow = blockIdx.x, t = threadIdx.x;
    const float* qr = q + (size_t)trow * (NH * HEADD);
    unsigned short* yr = Qb + (size_t)trow * (NH * HEADD);
    for (int i = t; i < NH * HEADD; i += 256) {
        int h = i / HEADD, d = i - h * HEADD;
        float val;
        if (d < NOPE) val = qr[i];
        else {
            int j = d - NOPE;
            int jj = j & 31;
            const float* pe = qr + h * HEADD + NOPE;
            float e = pe[2 * jj], o = pe[2 * jj + 1];
            float c = cosb[trow * 32 + jj], sn = sinb[trow * 32 + jj];
            val = (j < 32) ? (e * c - o * sn) : (o * c + e * sn);
        }
        yr[i] = f2bf(val);
    }
}

// ---------------- kvb[T,4096] fp32 -> K[T,H,192] bf16 (k_pe broadcast) ----------------
__global__ __launch_bounds__(256) void kprep_k(const float* __restrict__ kvb,
                                               const unsigned short* __restrict__ kpe,
                                               unsigned short* __restrict__ Kb) {
    int trow = blockIdx.x, t = threadIdx.x;
    const float* kr = kvb + (size_t)trow * 4096;
    unsigned short* kout = Kb + (size_t)trow * (NH * HEADD);
    for (int i = t; i < NH * HEADD; i += 256) {
        int h = i / HEADD, d = i - h * HEADD;
        kout[i] = (d < NOPE) ? f2bf(kr[h * 256 + d]) : kpe[trow * 64 + (d - NOPE)];
    }
}

// ---------------- kvb[T,4096] fp32 -> Vt[b*H+h][128][2048] bf16 (transposed) ----------
__global__ __launch_bounds__(256) void vtrans_k(const float* __restrict__ kvb,
                                                unsigned short* __restrict__ Vtg) {
    __shared__ unsigned short tile[64][132];
    int st = blockIdx.x, h = blockIdx.y, b = blockIdx.z;
    int t = threadIdx.x;
    int s0 = b * SEQ + st * 64;
    for (int c = t; c < 64 * 32; c += 256) {
        int r = c >> 5, d4 = (c & 31) * 4;
        float4 v = *(const float4*)(kvb + (size_t)(s0 + r) * 4096 + h * 256 + NOPE + d4);
        tile[r][d4]     = f2bf(v.x);
        tile[r][d4 + 1] = f2bf(v.y);
        tile[r][d4 + 2] = f2bf(v.z);
        tile[r][d4 + 3] = f2bf(v.w);
    }
    __syncthreads();
    int bh = b * NH + h;
    for (int c = t; c < 128 * 16; c += 256) {
        int d = c >> 4, s4 = (c & 15) * 4;
        unsigned short p0 = tile[s4][d], p1 = tile[s4 + 1][d];
        unsigned short p2 = tile[s4 + 2][d], p3 = tile[s4 + 3][d];
        uint2 o;
        o.x = (unsigned int)p0 | ((unsigned int)p1 << 16);
        o.y = (unsigned int)p2 | ((unsigned int)p3 << 16);
        *(uint2*)(Vtg + ((size_t)bh * VDIM + d) * SEQ + st * 64 + s4) = o;
    }
}

// ---------------- split-K causal flash attention, MFMA bf16 ----------------
// Key chunks of 512 (8 tiles of 64). Per (h,b): 80 (qt,chunk) blocks, enumerated
// chunk-ascending within qt-ascending. Block = 64 queries, 4 waves x 16 rows.
// Emits unnormalized partial O (bf16) + m,l (fp32) for a combine pass.
#define KS_STRIDE 200
#define VT_STRIDE 72
#define P_STRIDE  72
__global__ __launch_bounds__(256) void attn_mfma_k(const unsigned short* __restrict__ Qb,
                                                   const unsigned short* __restrict__ Kb,
                                                   const unsigned short* __restrict__ Vtg,
                                                   unsigned short* __restrict__ Opart,
                                                   float* __restrict__ Mbuf,
                                                   float* __restrict__ Lbuf) {
    const float SCALE = 0.07216878364870323f; // 192^-0.5
    __shared__ __align__(16) unsigned short Ks[64 * KS_STRIDE];
    __shared__ __align__(16) unsigned short Vts[128 * VT_STRIDE];
    __shared__ __align__(16) unsigned short Pw[4 * 16 * P_STRIDE];
    int xe = 79 - blockIdx.x;              // descending enumeration: big qt first
    int h  = blockIdx.y;
    int b  = blockIdx.z;
    // decode (qt, chunk) from xe: qt groups of size qt/8+1
    int qt = 0, accn = 0;
    while (true) { int c = (qt >> 3) + 1; if (xe < accn + c) break; accn += c; qt++; }
    int chunk = xe - accn;
    int t = threadIdx.x;
    int w = t >> 6, lane = t & 63;
    int l15 = lane & 15, quad = lane >> 4;
    int bh = b * NH + h;
    int q0 = b * SEQ + qt * 64;
    int qloc = qt * 64 + w * 16 + quad * 4;
    int flat = (b * NH + h) * 80 + xe;

    // preload Q fragments: wave w owns Q rows q0 + w*16 + (0..15)
    bf16x8 qf[6];
    {
        const unsigned short* qbase = Qb + ((size_t)(q0 + w * 16 + l15) * NH + h) * HEADD + quad * 8;
#pragma unroll
        for (int c = 0; c < 6; c++)
            qf[c] = *(const bf16x8*)(qbase + c * 32);
    }
    f32x4 acc_o[8];
    f32x4 zero = {0.f, 0.f, 0.f, 0.f};
#pragma unroll
    for (int j = 0; j < 8; j++) acc_o[j] = zero;
    float mrun[4], lrun[4];
#pragma unroll
    for (int r = 0; r < 4; r++) { mrun[r] = -1e30f; lrun[r] = 0.f; }

    uint4 kpre[6], vpre[4];
    auto prefetch = [&](int kt) {
        int k0 = b * SEQ + kt * 64;
#pragma unroll
        for (int j = 0; j < 6; j++) {
            int c = t + j * 256; int r = c / 24, cc = (c % 24) * 8;
            kpre[j] = *(const uint4*)(Kb + ((size_t)(k0 + r) * NH + h) * HEADD + cc);
        }
#pragma unroll
        for (int j = 0; j < 4; j++) {
            int c = t + j * 256; int d = c >> 3, cc = (c & 7) * 8;
            vpre[j] = *(const uint4*)(Vtg + ((size_t)bh * VDIM + d) * SEQ + kt * 64 + cc);
        }
    };

    unsigned short* Pme = Pw + w * 16 * P_STRIDE;
    int kt0 = chunk * 8, kt1 = min(kt0 + 7, qt);
    prefetch(kt0);
    for (int kt = kt0; kt <= kt1; kt++) {
        __syncthreads();   // previous iteration's LDS reads done
#pragma unroll
        for (int j = 0; j < 6; j++) {
            int c = t + j * 256; int r = c / 24, cc = (c % 24) * 8;
            *(uint4*)&Ks[r * KS_STRIDE + cc] = kpre[j];
        }
#pragma unroll
        for (int j = 0; j < 4; j++) {
            int c = t + j * 256; int d = c >> 3, cc = (c & 7) * 8;
            *(uint4*)&Vts[d * VT_STRIDE + cc] = vpre[j];
        }
        __syncthreads();
        if (kt < kt1) prefetch(kt + 1);   // overlaps S/softmax compute
        // S = Q K^T
        f32x4 acc_s[4];
#pragma unroll
        for (int j = 0; j < 4; j++) acc_s[j] = zero;
#pragma unroll
        for (int c = 0; c < 6; c++) {
#pragma unroll
            for (int j = 0; j < 4; j++) {
                bf16x8 kf = *(const bf16x8*)&Ks[(j * 16 + l15) * KS_STRIDE + c * 32 + quad * 8];
                acc_s[j] = __builtin_amdgcn_mfma_f32_16x16x32_bf16(qf[c], kf, acc_s[j], 0, 0, 0);
            }
        }
        float sv[4][4];
#pragma unroll
        for (int j = 0; j < 4; j++) {
            int kcol = kt * 64 + j * 16 + l15;
#pragma unroll
            for (int r = 0; r < 4; r++)
                sv[j][r] = (kcol > qloc + r) ? -1e30f : acc_s[j][r] * SCALE;
        }
        float alpha[4];
#pragma unroll
        for (int r = 0; r < 4; r++) {
            float v = fmaxf(fmaxf(sv[0][r], sv[1][r]), fmaxf(sv[2][r], sv[3][r]));
            v = fmaxf(v, __shfl_xor(v, 1));
            v = fmaxf(v, __shfl_xor(v, 2));
            v = fmaxf(v, __shfl_xor(v, 4));
            v = fmaxf(v, __shfl_xor(v, 8));
            float mnew = fmaxf(mrun[r], v);
            alpha[r] = __expf(mrun[r] - mnew);
            mrun[r] = mnew;
            float rs = 0.f;
#pragma unroll
            for (int j = 0; j < 4; j++) { float p = __expf(sv[j][r] - mnew); sv[j][r] = p; rs += p; }
            rs += __shfl_xor(rs, 1);
            rs += __shfl_xor(rs, 2);
            rs += __shfl_xor(rs, 4);
            rs += __shfl_xor(rs, 8);
            lrun[r] = lrun[r] * alpha[r] + rs;
        }
#pragma unroll
        for (int j = 0; j < 4; j++)
#pragma unroll
            for (int r = 0; r < 4; r++)
                Pme[(quad * 4 + r) * P_STRIDE + j * 16 + l15] = f2bf(sv[j][r]);
#pragma unroll
        for (int jt = 0; jt < 8; jt++)
#pragma unroll
            for (int r = 0; r < 4; r++) acc_o[jt][r] *= alpha[r];
        __syncthreads();
#pragma unroll
        for (int c2 = 0; c2 < 2; c2++) {
            bf16x8 pf = *(const bf16x8*)&Pme[l15 * P_STRIDE + c2 * 32 + quad * 8];
#pragma unroll
            for (int jt = 0; jt < 8; jt++) {
                bf16x8 vf = *(const bf16x8*)&Vts[(jt * 16 + l15) * VT_STRIDE + c2 * 32 + quad * 8];
                acc_o[jt] = __builtin_amdgcn_mfma_f32_16x16x32_bf16(pf, vf, acc_o[jt], 0, 0, 0);
            }
        }
    }
    // epilogue: unnormalized partial O (bf16) + m,l (fp32)
#pragma unroll
    for (int r = 0; r < 4; r++) {
        int row = w * 16 + quad * 4 + r;
        unsigned short* op = Opart + (size_t)flat * 8192 + row * 128 + l15;
#pragma unroll
        for (int jt = 0; jt < 8; jt++)
            op[jt * 16] = f2bf(acc_o[jt][r]);
        if (l15 == 0) {
            Mbuf[(size_t)flat * 64 + row] = mrun[r];
            Lbuf[(size_t)flat * 64 + row] = lrun[r];
        }
    }
}

// ---------------- combine: merge <=4 chunk partials, normalize, write attnb ----------
__global__ __launch_bounds__(256) void attn_combine_k(const unsigned short* __restrict__ Opart,
                                                      const float* __restrict__ Mbuf,
                                                      const float* __restrict__ Lbuf,
                                                      unsigned short* __restrict__ attnb) {
    int qt = blockIdx.x, h = blockIdx.y, b = blockIdx.z;
    int nch = (qt >> 3) + 1;
    int F = 0;
    for (int q = 0; q < qt; q++) F += (q >> 3) + 1;
    int flat0 = (b * NH + h) * 80 + F;
    int t = threadIdx.x;
    int row = t >> 2, d0 = (t & 3) * 32;
    float mc[4], lc[4];
    float mstar = -1e30f;
    for (int c = 0; c < nch; c++) {
        mc[c] = Mbuf[(size_t)(flat0 + c) * 64 + row];
        lc[c] = Lbuf[(size_t)(flat0 + c) * 64 + row];
        mstar = fmaxf(mstar, mc[c]);
    }
    float L = 0.f, wgt[4];
    for (int c = 0; c < nch; c++) { wgt[c] = __expf(mc[c] - mstar); L += wgt[c] * lc[c]; }
    float invL = 1.f / L;
    float acc[32];
#pragma unroll
    for (int j = 0; j < 32; j++) acc[j] = 0.f;
    for (int c = 0; c < nch; c++) {
        const unsigned short* src = Opart + (size_t)(flat0 + c) * 8192 + row * 128 + d0;
        float wc = wgt[c];
#pragma unroll
        for (int g = 0; g < 4; g++) {
            uint4 u = *(const uint4*)(src + g * 8);
            const unsigned short* sp = (const unsigned short*)&u;
#pragma unroll
            for (int j = 0; j < 8; j++) acc[g * 8 + j] += wc * bf2f(sp[j]);
        }
    }
    unsigned short* dst = attnb + (size_t)(b * SEQ + qt * 64 + row) * 2048 + h * 128 + d0;
#pragma unroll
    for (int g = 0; g < 4; g++) {
        uint4 o;
        unsigned short* sp = (unsigned short*)&o;
#pragma unroll
        for (int j = 0; j < 8; j++) sp[j] = f2bf(acc[g * 8 + j] * invL);
        *(uint4*)(dst + g * 8) = o;
    }
}

// =====================================================================
extern "C" void kernel_launch(void* const* d_in, const int* in_sizes, int n_in,
                              void* d_out, int out_size, void* d_ws, size_t ws_size,
                              hipStream_t stream) {
    const float* hs     = (const float*)d_in[0];
    const float* cosb   = (const float*)d_in[1];
    const float* sinb   = (const float*)d_in[2];
    const float* w_q_a  = (const float*)d_in[3];
    const float* q_ln   = (const float*)d_in[4];
    const float* w_q_b  = (const float*)d_in[5];
    const float* w_kv_a = (const float*)d_in[6];
    const float* kv_ln  = (const float*)d_in[7];
    const float* w_kv_b = (const float*)d_in[8];
    const float* w_o    = (const float*)d_in[9];
    float* out = (float*)d_out;

    char* base = (char*)d_ws;
    size_t off = 0;
    auto take = [&](size_t bytes) { void* p = base + off; off += (bytes + 255) & ~(size_t)255; return p; };
    unsigned short* wqaT  = (unsigned short*)take((size_t)1536 * 2048 * 2);
    unsigned short* wqbT  = (unsigned short*)take((size_t)3072 * 1536 * 2);
    unsigned short* wkvaT = (unsigned short*)take((size_t)576 * 2048 * 2);
    unsigned short* wkvbT = (unsigned short*)take((size_t)4096 * 512 * 2);
    unsigned short* woT   = (unsigned short*)take((size_t)2048 * 2048 * 2);
    unsigned short* hsb   = (unsigned short*)take((size_t)TT * DD * 2);
    unsigned short* qan   = (unsigned short*)take((size_t)TT * 1536 * 2);
    unsigned short* ckvn  = (unsigned short*)take((size_t)TT * 512 * 2);
    unsigned short* kpe   = (unsigned short*)take((size_t)TT * 64 * 2);
    unsigned short* Qbuf  = (unsigned short*)take((size_t)TT * NH * HEADD * 2);
    unsigned short* Kbuf  = (unsigned short*)take((size_t)TT * NH * HEADD * 2);
    unsigned short* Vtg   = (unsigned short*)take((size_t)TT * NH * VDIM * 2);  // [b*H+h][128][2048]
    unsigned short* attnb = (unsigned short*)take((size_t)TT * 2048 * 2);
    char* Sreg = (char*)take((size_t)TT * 4096 * 4);   // 64 MB multipurpose
    float* S = (float*)Sreg;                            // fp32 GEMM scratch (pre-attention)
    // post-vtrans overlays (S's GEMM lifetime has ended by attention time):
    unsigned short* Opart = (unsigned short*)Sreg;                       // 2560*64*128 bf16 = 41.9MB
    float* Mbuf = (float*)(Sreg + (size_t)2560 * 8192 * 2);              // 2560*64 f32
    float* Lbuf = Mbuf + (size_t)2560 * 64;

    // 0. activations + weights to bf16 (weights transposed to [N,K])
    cvt_bf16_k<<<(TT * DD) / 1024, 256, 0, stream>>>(hs, hsb, TT * DD);
    transpose_cvt_k<<<dim3(1536 / 32, 2048 / 32), 256, 0, stream>>>(w_q_a, wqaT, 2048, 1536);
    transpose_cvt_k<<<dim3(3072 / 32, 1536 / 32), 256, 0, stream>>>(w_q_b, wqbT, 1536, 3072);
    transpose_cvt_k<<<dim3(18, 2048 / 32), 256, 0, stream>>>(w_kv_a, wkvaT, 2048, 576);
    transpose_cvt_k<<<dim3(4096 / 32, 512 / 32), 256, 0, stream>>>(w_kv_b, wkvbT, 512, 4096);
    transpose_cvt_k<<<dim3(2048 / 32, 2048 / 32), 256, 0, stream>>>(w_o, woT, 2048, 2048);

    // 1. q_a = hs @ w_q_a ; rmsnorm -> qan (bf16)
    gemm_bf16_k<<<dim3(12, 32), 256, 0, stream>>>(hsb, wqaT, S, 4096, 1536, 2048);
    rmsnorm_k<<<4096, 256, 0, stream>>>(S, q_ln, qan, 1536);
    // 2. ckv = hs @ w_kv_a ; rmsnorm(512) + rope(k_pe)
    gemm_bf16_k<<<dim3(5, 32), 256, 0, stream>>>(hsb, wkvaT, S, 4096, 576, 2048);
    kvprep_k<<<4096, 256, 0, stream>>>(S, kv_ln, cosb, sinb, ckvn, kpe);
    // 3. q = qan @ w_q_b ; rope -> Qbuf
    gemm_bf16_k<<<dim3(24, 32), 256, 0, stream>>>(qan, wqbT, S, 4096, 3072, 1536);
    qprep_k<<<4096, 256, 0, stream>>>(S, cosb, sinb, Qbuf);
    // 4. kv = ckvn @ w_kv_b ; K (with k_pe broadcast), V transposed to [bh][d][s]
    gemm_bf16_k<<<dim3(32, 32), 256, 0, stream>>>(ckvn, wkvbT, S, 4096, 4096, 512);
    kprep_k<<<4096, 256, 0, stream>>>(S, kpe, Kbuf);
    vtrans_k<<<dim3(32, 16, 2), 256, 0, stream>>>(S, Vtg);
    // 5. split-K attention (2560 blocks) + combine
    attn_mfma_k<<<dim3(80, 16, 2), 256, 0, stream>>>(Qbuf, Kbuf, Vtg, Opart, Mbuf, Lbuf);
    attn_combine_k<<<dim3(32, 16, 2), 256, 0, stream>>>(Opart, Mbuf, Lbuf, attnb);
    // 6. out = attn @ w_o
    gemm_bf16_k<<<dim3(16, 32), 256, 0, stream>>>(attnb, woT, out, 4096, 2048, 2048);
}

// Round 4
// 628.176 us; speedup vs baseline: 3.9803x; 1.2051x over previous
//
#include <hip/hip_runtime.h>
#include <cstdint>
#include <cstddef>

// Shapes are fixed by setup_inputs(): T=4096, D=2048, B=2, S=2048.
#define TT 4096
#define DD 2048
#define NH 16
#define HEADD 192
#define NOPE 128
#define VDIM 128
#define SEQ 2048

typedef __bf16 bf16x8 __attribute__((ext_vector_type(8)));
typedef float f32x4 __attribute__((ext_vector_type(4)));
typedef unsigned int u32;

__device__ __forceinline__ float bf2f(unsigned short u) {
    union { unsigned int i; float f; } v; v.i = ((unsigned int)u) << 16; return v.f;
}
__device__ __forceinline__ unsigned short f2bf(float f) {
    union { float f; unsigned int i; } v; v.f = f;
    unsigned int r = v.i + 0x7FFFu + ((v.i >> 16) & 1u);
    return (unsigned short)(r >> 16);
}
// async global->LDS, 16B per lane; LDS dest = wave-uniform base + lane*16
__device__ __forceinline__ void gload16(const unsigned short* g, unsigned short* l) {
    __builtin_amdgcn_global_load_lds((const __attribute__((address_space(1))) u32*)g,
                                     (__attribute__((address_space(3))) u32*)l, 16, 0, 0);
}

// ---------------- fp32 -> bf16 elementwise ----------------
__global__ __launch_bounds__(256) void cvt_bf16_k(const float* __restrict__ x,
                                                  unsigned short* __restrict__ y, int n) {
    int i = (blockIdx.x * 256 + threadIdx.x) * 4;
    if (i < n) {
        float4 v = *(const float4*)(x + i);
        uint2 o;
        o.x = (unsigned int)f2bf(v.x) | ((unsigned int)f2bf(v.y) << 16);
        o.y = (unsigned int)f2bf(v.z) | ((unsigned int)f2bf(v.w) << 16);
        *(uint2*)(y + i) = o;
    }
}

// ---------------- W[K,N] fp32 -> Wt[N,K] bf16 ----------------
__global__ __launch_bounds__(256) void transpose_cvt_k(const float* __restrict__ W,
                                                       unsigned short* __restrict__ Wt,
                                                       int K, int N) {
    __shared__ float tile[32][33];
    int n0 = blockIdx.x * 32, k0 = blockIdx.y * 32;
    int t = threadIdx.x, lr = t >> 5, lc = t & 31;
#pragma unroll
    for (int p = 0; p < 4; p++) {
        int k = k0 + lr + p * 8, n = n0 + lc;
        tile[lr + p * 8][lc] = (k < K && n < N) ? W[(size_t)k * N + n] : 0.f;
    }
    __syncthreads();
#pragma unroll
    for (int p = 0; p < 4; p++) {
        int n = n0 + lr + p * 8, k = k0 + lc;
        if (n < N && k < K) Wt[(size_t)n * K + k] = f2bf(tile[lc][lr + p * 8]);
    }
}

// ---------------- C[M,N] fp32 = A[M,K] bf16 @ Bt[N,K] bf16 ----------------
// 128x128 tile, BK=32, async global_load_lds staging (m97 pattern).
__global__ __launch_bounds__(256) void gemm_bf16_k(const unsigned short* __restrict__ A,
                                                   const unsigned short* __restrict__ Bt,
                                                   float* __restrict__ C,
                                                   int M, int N, int K) {
    __shared__ __align__(16) unsigned short As[128 * 32];
    __shared__ __align__(16) unsigned short Bs[128 * 32];
    int bm = blockIdx.y * 128, bn = blockIdx.x * 128;
    int t = threadIdx.x;
    int wave = t >> 6, lane = t & 63;
    int wr = (wave >> 1) * 64, wc = (wave & 1) * 64;
    int l15 = lane & 15, quad = lane >> 4;
    f32x4 acc[4][4];
    f32x4 zero = {0.f, 0.f, 0.f, 0.f};
#pragma unroll
    for (int i = 0; i < 4; i++)
#pragma unroll
        for (int j = 0; j < 4; j++) acc[i][j] = zero;
    int r0 = 16 * (2 * wave) + (lane >> 2);
    int cOff = (lane & 3) * 8;   // shorts
    const unsigned short* gA0 = A + (size_t)(bm + r0) * K + cOff;
    const unsigned short* gA1 = A + (size_t)(bm + r0 + 16) * K + cOff;
    const unsigned short* gB0 = Bt + (size_t)(bn + r0) * K + cOff;
    const unsigned short* gB1 = Bt + (size_t)(bn + r0 + 16) * K + cOff;
    unsigned short* lA0 = &As[(2 * wave) * 512];
    unsigned short* lA1 = &As[(2 * wave + 1) * 512];
    unsigned short* lB0 = &Bs[(2 * wave) * 512];
    unsigned short* lB1 = &Bs[(2 * wave + 1) * 512];
    for (int k0 = 0; k0 < K; k0 += 32) {
        gload16(gA0 + k0, lA0);
        gload16(gA1 + k0, lA1);
        gload16(gB0 + k0, lB0);
        gload16(gB1 + k0, lB1);
        __syncthreads();   // drains vmcnt: async loads landed
        bf16x8 af[4], bfr[4];
#pragma unroll
        for (int i = 0; i < 4; i++)
            af[i] = *(const bf16x8*)&As[(wr + i * 16 + l15) * 32 + quad * 8];
#pragma unroll
        for (int j = 0; j < 4; j++)
            bfr[j] = *(const bf16x8*)&Bs[(wc + j * 16 + l15) * 32 + quad * 8];
#pragma unroll
        for (int i = 0; i < 4; i++)
#pragma unroll
            for (int j = 0; j < 4; j++)
                acc[i][j] = __builtin_amdgcn_mfma_f32_16x16x32_bf16(af[i], bfr[j], acc[i][j], 0, 0, 0);
        __syncthreads();
    }
#pragma unroll
    for (int i = 0; i < 4; i++) {
        int row = bm + wr + i * 16 + quad * 4;
#pragma unroll
        for (int j = 0; j < 4; j++) {
            int col = bn + wc + j * 16 + l15;
            if (col < N) {
                float* cp = C + (size_t)row * N + col;
#pragma unroll
                for (int r = 0; r < 4; r++) cp[(size_t)r * N] = acc[i][j][r];
            }
        }
    }
}

// ---------------- RMSNorm (block per row) ----------------
__global__ __launch_bounds__(256) void rmsnorm_k(const float* __restrict__ x,
                                                 const float* __restrict__ w,
                                                 unsigned short* __restrict__ y, int cols) {
    int row = blockIdx.x, t = threadIdx.x;
    const float* xr = x + (size_t)row * cols;
    float s = 0.f;
    for (int i = t; i < cols; i += 256) { float v = xr[i]; s += v * v; }
    __shared__ float red[256];
    red[t] = s; __syncthreads();
    for (int o = 128; o > 0; o >>= 1) { if (t < o) red[t] += red[t + o]; __syncthreads(); }
    float scale = rsqrtf(red[0] / (float)cols + 1e-6f);
    unsigned short* yr = y + (size_t)row * cols;
    for (int i = t; i < cols; i += 256) yr[i] = f2bf(xr[i] * scale * w[i]);
}

// ---------------- ckv[T,576] -> rmsnorm(512) bf16 + roped k_pe[64] bf16 ----------------
__global__ __launch_bounds__(256) void kvprep_k(const float* __restrict__ ckv,
                                                const float* __restrict__ w,
                                                const float* __restrict__ cosb,
                                                const float* __restrict__ sinb,
                                                unsigned short* __restrict__ ckvn,
                                                unsigned short* __restrict__ kpe) {
    int row = blockIdx.x, t = threadIdx.x;
    const float* xr = ckv + (size_t)row * 576;
    float s = 0.f;
#pragma unroll
    for (int i = t; i < 512; i += 256) { float v = xr[i]; s += v * v; }
    __shared__ float red[256];
    red[t] = s; __syncthreads();
    for (int o = 128; o > 0; o >>= 1) { if (t < o) red[t] += red[t + o]; __syncthreads(); }
    float scale = rsqrtf(red[0] / 512.f + 1e-6f);
    unsigned short* yr = ckvn + (size_t)row * 512;
#pragma unroll
    for (int i = t; i < 512; i += 256) yr[i] = f2bf(xr[i] * scale * w[i]);
    if (t < 32) {
        float e = xr[512 + 2 * t], o = xr[512 + 2 * t + 1];
        float c = cosb[row * 32 + t], sn = sinb[row * 32 + t];
        kpe[row * 64 + t]      = f2bf(e * c - o * sn);
        kpe[row * 64 + 32 + t] = f2bf(o * c + e * sn);
    }
}

// ---------------- q[T, H*192] fp32 -> Q bf16 with rope on dims 128..191 ----------------
__global__ __launch_bounds__(256) void qprep_k(const float* __restrict__ q,
                                               const float* __restrict__ cosb,
                                               const float* __restrict__ sinb,
                                               unsigned short* __restrict__ Qb) {
    int trow = blockIdx.x, t = threadIdx.x;
    const float* qr = q + (size_t)trow * (NH * HEADD);
    unsigned short* yr = Qb + (size_t)trow * (NH * HEADD);
    for (int i = t; i < NH * HEADD; i += 256) {
        int h = i / HEADD, d = i - h * HEADD;
        float val;
        if (d < NOPE) val = qr[i];
        else {
            int j = d - NOPE;
            int jj = j & 31;
            const float* pe = qr + h * HEADD + NOPE;
            float e = pe[2 * jj], o = pe[2 * jj + 1];
            float c = cosb[trow * 32 + jj], sn = sinb[trow * 32 + jj];
            val = (j < 32) ? (e * c - o * sn) : (o * c + e * sn);
        }
        yr[i] = f2bf(val);
    }
}

// Attention-ready padded tiled layouts (staged whole via global_load_lds;
// pad bytes are loaded into LDS but never ds_read):
//   Kb2 [bh][kt=32][64 rows][KS_STRIDE=200]  (25600 B / tile)
//   Vt2 [bh][kt=32][128 dims][VT_STRIDE=72]  (18432 B / tile)
#define KS_STRIDE 200
#define VT_STRIDE 72
#define P_STRIDE  72

// ---------------- kvb[T,4096] fp32 -> Kb2 (k_pe broadcast) ----------------
__global__ __launch_bounds__(256) void kprep_k(const float* __restrict__ kvb,
                                               const unsigned short* __restrict__ kpe,
                                               unsigned short* __restrict__ Kb2) {
    int trow = blockIdx.x, t = threadIdx.x;
    int b = trow >> 11, s = trow & 2047;
    int ktile = s >> 6, srow = s & 63;
    const float* kr = kvb + (size_t)trow * 4096;
    for (int i = t; i < NH * HEADD; i += 256) {
        int h = i / HEADD, d = i - h * HEADD;
        unsigned short v = (d < NOPE) ? f2bf(kr[h * 256 + d]) : kpe[trow * 64 + (d - NOPE)];
        Kb2[(((size_t)(b * NH + h) * 32 + ktile) * 64 + srow) * KS_STRIDE + d] = v;
    }
}

// ---------------- kvb[T,4096] fp32 -> Vt2 (transposed per 64-key tile) ----------
__global__ __launch_bounds__(256) void vtrans_k(const float* __restrict__ kvb,
                                                unsigned short* __restrict__ Vt2) {
    __shared__ unsigned short tile[64][132];
    int st = blockIdx.x, h = blockIdx.y, b = blockIdx.z;
    int t = threadIdx.x;
    int s0 = b * SEQ + st * 64;
    for (int c = t; c < 64 * 32; c += 256) {
        int r = c >> 5, d4 = (c & 31) * 4;
        float4 v = *(const float4*)(kvb + (size_t)(s0 + r) * 4096 + h * 256 + NOPE + d4);
        tile[r][d4]     = f2bf(v.x);
        tile[r][d4 + 1] = f2bf(v.y);
        tile[r][d4 + 2] = f2bf(v.z);
        tile[r][d4 + 3] = f2bf(v.w);
    }
    __syncthreads();
    int bh = b * NH + h;
    for (int c = t; c < 128 * 16; c += 256) {
        int d = c >> 4, s4 = (c & 15) * 4;
        unsigned short p0 = tile[s4][d], p1 = tile[s4 + 1][d];
        unsigned short p2 = tile[s4 + 2][d], p3 = tile[s4 + 3][d];
        uint2 o;
        o.x = (unsigned int)p0 | ((unsigned int)p1 << 16);
        o.y = (unsigned int)p2 | ((unsigned int)p3 << 16);
        *(uint2*)(Vt2 + (((size_t)bh * 32 + st) * 128 + d) * VT_STRIDE + s4) = o;
    }
}

// ---------------- split-K causal flash attention, MFMA bf16 ----------------
// Key chunks of 512 (8 tiles of 64). Per (h,b): 80 (qt,chunk) blocks.
// Block = 64 queries, 4 waves x 16 rows. K/V tiles staged via async
// global_load_lds (43 x 1KB wave-chunks per tile) -> no VGPR round-trip.
__global__ __launch_bounds__(256) void attn_mfma_k(const unsigned short* __restrict__ Qb,
                                                   const unsigned short* __restrict__ Kb2,
                                                   const unsigned short* __restrict__ Vt2,
                                                   unsigned short* __restrict__ Opart,
                                                   float* __restrict__ Mbuf,
                                                   float* __restrict__ Lbuf) {
    const float SCALE = 0.07216878364870323f; // 192^-0.5
    __shared__ __align__(16) unsigned short Ks[64 * KS_STRIDE];
    __shared__ __align__(16) unsigned short Vts[128 * VT_STRIDE];
    __shared__ __align__(16) unsigned short Pw[4 * 16 * P_STRIDE];
    int xe = 79 - blockIdx.x;              // descending enumeration: big qt first
    int h  = blockIdx.y;
    int b  = blockIdx.z;
    int qt = 0, accn = 0;
    while (true) { int c = (qt >> 3) + 1; if (xe < accn + c) break; accn += c; qt++; }
    int chunk = xe - accn;
    int t = threadIdx.x;
    int w = t >> 6, lane = t & 63;
    int l15 = lane & 15, quad = lane >> 4;
    int bh = b * NH + h;
    int q0 = b * SEQ + qt * 64;
    int qloc = qt * 64 + w * 16 + quad * 4;
    int flat = bh * 80 + xe;

    // preload Q fragments: wave w owns Q rows q0 + w*16 + (0..15)
    bf16x8 qf[6];
    {
        const unsigned short* qbase = Qb + ((size_t)(q0 + w * 16 + l15) * NH + h) * HEADD + quad * 8;
#pragma unroll
        for (int c = 0; c < 6; c++)
            qf[c] = *(const bf16x8*)(qbase + c * 32);
    }
    f32x4 acc_o[8];
    f32x4 zero = {0.f, 0.f, 0.f, 0.f};
#pragma unroll
    for (int j = 0; j < 8; j++) acc_o[j] = zero;
    float mrun[4], lrun[4];
#pragma unroll
    for (int r = 0; r < 4; r++) { mrun[r] = -1e30f; lrun[r] = 0.f; }

    unsigned short* Pme = Pw + w * 16 * P_STRIDE;
    int kt0 = chunk * 8, kt1 = min(kt0 + 7, qt);
    int cbeg = w * 11, cend = min(cbeg + 11, 43);
    for (int kt = kt0; kt <= kt1; kt++) {
        __syncthreads();   // all waves done reading Ks/Vts from prev iter
        // async stage K tile (25 KB) + Vt tile (18 KB): 43 x 1KB wave-chunks
        {
            const unsigned short* kg = Kb2 + ((size_t)bh * 32 + kt) * (64 * KS_STRIDE) + lane * 8;
            const unsigned short* vg = Vt2 + ((size_t)bh * 32 + kt) * (128 * VT_STRIDE) + lane * 8;
            for (int c = cbeg; c < cend; c++) {
                if (c < 25) gload16(kg + c * 512, &Ks[c * 512]);
                else        gload16(vg + (c - 25) * 512, &Vts[(c - 25) * 512]);
            }
        }
        __syncthreads();   // vmcnt drained: tiles resident in LDS
        // S = Q K^T
        f32x4 acc_s[4];
#pragma unroll
        for (int j = 0; j < 4; j++) acc_s[j] = zero;
#pragma unroll
        for (int c = 0; c < 6; c++) {
#pragma unroll
            for (int j = 0; j < 4; j++) {
                bf16x8 kf = *(const bf16x8*)&Ks[(j * 16 + l15) * KS_STRIDE + c * 32 + quad * 8];
                acc_s[j] = __builtin_amdgcn_mfma_f32_16x16x32_bf16(qf[c], kf, acc_s[j], 0, 0, 0);
            }
        }
        float sv[4][4];
#pragma unroll
        for (int j = 0; j < 4; j++) {
            int kcol = kt * 64 + j * 16 + l15;
#pragma unroll
            for (int r = 0; r < 4; r++)
                sv[j][r] = (kcol > qloc + r) ? -1e30f : acc_s[j][r] * SCALE;
        }
        float alpha[4];
#pragma unroll
        for (int r = 0; r < 4; r++) {
            float v = fmaxf(fmaxf(sv[0][r], sv[1][r]), fmaxf(sv[2][r], sv[3][r]));
            v = fmaxf(v, __shfl_xor(v, 1));
            v = fmaxf(v, __shfl_xor(v, 2));
            v = fmaxf(v, __shfl_xor(v, 4));
            v = fmaxf(v, __shfl_xor(v, 8));
            float mnew = fmaxf(mrun[r], v);
            alpha[r] = __expf(mrun[r] - mnew);
            mrun[r] = mnew;
            float rs = 0.f;
#pragma unroll
            for (int j = 0; j < 4; j++) { float p = __expf(sv[j][r] - mnew); sv[j][r] = p; rs += p; }
            rs += __shfl_xor(rs, 1);
            rs += __shfl_xor(rs, 2);
            rs += __shfl_xor(rs, 4);
            rs += __shfl_xor(rs, 8);
            lrun[r] = lrun[r] * alpha[r] + rs;
        }
#pragma unroll
        for (int j = 0; j < 4; j++)
#pragma unroll
            for (int r = 0; r < 4; r++)
                Pme[(quad * 4 + r) * P_STRIDE + j * 16 + l15] = f2bf(sv[j][r]);
#pragma unroll
        for (int jt = 0; jt < 8; jt++)
#pragma unroll
            for (int r = 0; r < 4; r++) acc_o[jt][r] *= alpha[r];
        __syncthreads();
#pragma unroll
        for (int c2 = 0; c2 < 2; c2++) {
            bf16x8 pf = *(const bf16x8*)&Pme[l15 * P_STRIDE + c2 * 32 + quad * 8];
#pragma unroll
            for (int jt = 0; jt < 8; jt++) {
                bf16x8 vf = *(const bf16x8*)&Vts[(jt * 16 + l15) * VT_STRIDE + c2 * 32 + quad * 8];
                acc_o[jt] = __builtin_amdgcn_mfma_f32_16x16x32_bf16(pf, vf, acc_o[jt], 0, 0, 0);
            }
        }
    }
    // epilogue: unnormalized partial O (bf16) + m,l (fp32)
#pragma unroll
    for (int r = 0; r < 4; r++) {
        int row = w * 16 + quad * 4 + r;
        unsigned short* op = Opart + (size_t)flat * 8192 + row * 128 + l15;
#pragma unroll
        for (int jt = 0; jt < 8; jt++)
            op[jt * 16] = f2bf(acc_o[jt][r]);
        if (l15 == 0) {
            Mbuf[(size_t)flat * 64 + row] = mrun[r];
            Lbuf[(size_t)flat * 64 + row] = lrun[r];
        }
    }
}

// ---------------- combine: merge <=4 chunk partials, normalize, write attnb ----------
__global__ __launch_bounds__(256) void attn_combine_k(const unsigned short* __restrict__ Opart,
                                                      const float* __restrict__ Mbuf,
                                                      const float* __restrict__ Lbuf,
                                                      unsigned short* __restrict__ attnb) {
    int qt = blockIdx.x, h = blockIdx.y, b = blockIdx.z;
    int nch = (qt >> 3) + 1;
    int F = 0;
    for (int q = 0; q < qt; q++) F += (q >> 3) + 1;
    int flat0 = (b * NH + h) * 80 + F;
    int t = threadIdx.x;
    int row = t >> 2, d0 = (t & 3) * 32;
    float mc[4], lc[4], wgt[4];
    float mstar = -1e30f;
#pragma unroll
    for (int c = 0; c < 4; c++) {
        if (c < nch) {
            mc[c] = Mbuf[(size_t)(flat0 + c) * 64 + row];
            lc[c] = Lbuf[(size_t)(flat0 + c) * 64 + row];
        } else { mc[c] = -1e30f; lc[c] = 0.f; }
        mstar = fmaxf(mstar, mc[c]);
    }
    float L = 0.f;
#pragma unroll
    for (int c = 0; c < 4; c++) { wgt[c] = __expf(mc[c] - mstar); L += wgt[c] * lc[c]; }
    float invL = 1.f / L;
    float acc[32];
#pragma unroll
    for (int j = 0; j < 32; j++) acc[j] = 0.f;
#pragma unroll
    for (int c = 0; c < 4; c++) {
        if (c < nch) {
            const unsigned short* src = Opart + (size_t)(flat0 + c) * 8192 + row * 128 + d0;
            float wc = wgt[c];
#pragma unroll
            for (int g = 0; g < 4; g++) {
                uint4 u = *(const uint4*)(src + g * 8);
                const unsigned short* sp = (const unsigned short*)&u;
#pragma unroll
                for (int j = 0; j < 8; j++) acc[g * 8 + j] += wc * bf2f(sp[j]);
            }
        }
    }
    unsigned short* dst = attnb + (size_t)(b * SEQ + qt * 64 + row) * 2048 + h * 128 + d0;
#pragma unroll
    for (int g = 0; g < 4; g++) {
        uint4 o;
        unsigned short* sp = (unsigned short*)&o;
#pragma unroll
        for (int j = 0; j < 8; j++) sp[j] = f2bf(acc[g * 8 + j] * invL);
        *(uint4*)(dst + g * 8) = o;
    }
}

// =====================================================================
extern "C" void kernel_launch(void* const* d_in, const int* in_sizes, int n_in,
                              void* d_out, int out_size, void* d_ws, size_t ws_size,
                              hipStream_t stream) {
    const float* hs     = (const float*)d_in[0];
    const float* cosb   = (const float*)d_in[1];
    const float* sinb   = (const float*)d_in[2];
    const float* w_q_a  = (const float*)d_in[3];
    const float* q_ln   = (const float*)d_in[4];
    const float* w_q_b  = (const float*)d_in[5];
    const float* w_kv_a = (const float*)d_in[6];
    const float* kv_ln  = (const float*)d_in[7];
    const float* w_kv_b = (const float*)d_in[8];
    const float* w_o    = (const float*)d_in[9];
    float* out = (float*)d_out;

    char* base = (char*)d_ws;
    size_t off = 0;
    auto take = [&](size_t bytes) { void* p = base + off; off += (bytes + 255) & ~(size_t)255; return p; };
    unsigned short* wqaT  = (unsigned short*)take((size_t)1536 * 2048 * 2);
    unsigned short* wqbT  = (unsigned short*)take((size_t)3072 * 1536 * 2);
    unsigned short* wkvaT = (unsigned short*)take((size_t)576 * 2048 * 2);
    unsigned short* wkvbT = (unsigned short*)take((size_t)4096 * 512 * 2);
    unsigned short* woT   = (unsigned short*)take((size_t)2048 * 2048 * 2);
    unsigned short* hsb   = (unsigned short*)take((size_t)TT * DD * 2);
    unsigned short* qan   = (unsigned short*)take((size_t)TT * 1536 * 2);
    unsigned short* ckvn  = (unsigned short*)take((size_t)TT * 512 * 2);
    unsigned short* kpe   = (unsigned short*)take((size_t)TT * 64 * 2);
    unsigned short* Qbuf  = (unsigned short*)take((size_t)TT * NH * HEADD * 2);
    unsigned short* Kb2   = (unsigned short*)take((size_t)32 * 32 * 64 * KS_STRIDE * 2);   // 26.2 MB
    unsigned short* Vt2   = (unsigned short*)take((size_t)32 * 32 * 128 * VT_STRIDE * 2);  // 18.9 MB
    unsigned short* attnb = (unsigned short*)take((size_t)TT * 2048 * 2);
    char* Sreg = (char*)take((size_t)TT * 4096 * 4);   // 64 MB multipurpose
    float* S = (float*)Sreg;                            // fp32 GEMM scratch (pre-attention)
    unsigned short* Opart = (unsigned short*)Sreg;                       // 2560*64*128 bf16
    float* Mbuf = (float*)(Sreg + (size_t)2560 * 8192 * 2);
    float* Lbuf = Mbuf + (size_t)2560 * 64;

    // 0. activations + weights to bf16 (weights transposed to [N,K])
    cvt_bf16_k<<<(TT * DD) / 1024, 256, 0, stream>>>(hs, hsb, TT * DD);
    transpose_cvt_k<<<dim3(1536 / 32, 2048 / 32), 256, 0, stream>>>(w_q_a, wqaT, 2048, 1536);
    transpose_cvt_k<<<dim3(3072 / 32, 1536 / 32), 256, 0, stream>>>(w_q_b, wqbT, 1536, 3072);
    transpose_cvt_k<<<dim3(18, 2048 / 32), 256, 0, stream>>>(w_kv_a, wkvaT, 2048, 576);
    transpose_cvt_k<<<dim3(4096 / 32, 512 / 32), 256, 0, stream>>>(w_kv_b, wkvbT, 512, 4096);
    transpose_cvt_k<<<dim3(2048 / 32, 2048 / 32), 256, 0, stream>>>(w_o, woT, 2048, 2048);

    // 1. q_a = hs @ w_q_a ; rmsnorm -> qan (bf16)
    gemm_bf16_k<<<dim3(12, 32), 256, 0, stream>>>(hsb, wqaT, S, 4096, 1536, 2048);
    rmsnorm_k<<<4096, 256, 0, stream>>>(S, q_ln, qan, 1536);
    // 2. ckv = hs @ w_kv_a ; rmsnorm(512) + rope(k_pe)
    gemm_bf16_k<<<dim3(5, 32), 256, 0, stream>>>(hsb, wkvaT, S, 4096, 576, 2048);
    kvprep_k<<<4096, 256, 0, stream>>>(S, kv_ln, cosb, sinb, ckvn, kpe);
    // 3. q = qan @ w_q_b ; rope -> Qbuf
    gemm_bf16_k<<<dim3(24, 32), 256, 0, stream>>>(qan, wqbT, S, 4096, 3072, 1536);
    qprep_k<<<4096, 256, 0, stream>>>(S, cosb, sinb, Qbuf);
    // 4. kv = ckvn @ w_kv_b ; K -> Kb2 (padded tiled), V -> Vt2 (transposed tiled)
    gemm_bf16_k<<<dim3(32, 32), 256, 0, stream>>>(ckvn, wkvbT, S, 4096, 4096, 512);
    kprep_k<<<4096, 256, 0, stream>>>(S, kpe, Kb2);
    vtrans_k<<<dim3(32, 16, 2), 256, 0, stream>>>(S, Vt2);
    // 5. split-K attention (2560 blocks) + combine
    attn_mfma_k<<<dim3(80, 16, 2), 256, 0, stream>>>(Qbuf, Kb2, Vt2, Opart, Mbuf, Lbuf);
    attn_combine_k<<<dim3(32, 16, 2), 256, 0, stream>>>(Opart, Mbuf, Lbuf, attnb);
    // 6. out = attn @ w_o
    gemm_bf16_k<<<dim3(16, 32), 256, 0, stream>>>(attnb, woT, out, 4096, 2048, 2048);
}

// Round 5
// 595.237 us; speedup vs baseline: 4.2006x; 1.0553x over previous
//
#include <hip/hip_runtime.h>
#include <cstdint>
#include <cstddef>

// Shapes are fixed by setup_inputs(): T=4096, D=2048, B=2, S=2048.
#define TT 4096
#define DD 2048
#define NH 16
#define HEADD 192
#define NOPE 128
#define VDIM 128
#define SEQ 2048

typedef __bf16 bf16x8 __attribute__((ext_vector_type(8)));
typedef float f32x4 __attribute__((ext_vector_type(4)));
typedef unsigned int u32;

__device__ __forceinline__ float bf2f(unsigned short u) {
    union { unsigned int i; float f; } v; v.i = ((unsigned int)u) << 16; return v.f;
}
__device__ __forceinline__ unsigned short f2bf(float f) {
    union { float f; unsigned int i; } v; v.f = f;
    unsigned int r = v.i + 0x7FFFu + ((v.i >> 16) & 1u);
    return (unsigned short)(r >> 16);
}
// async global->LDS, 16B per lane; LDS dest = wave-uniform base + lane*16
__device__ __forceinline__ void gload16(const unsigned short* g, unsigned short* l) {
    __builtin_amdgcn_global_load_lds((const __attribute__((address_space(1))) u32*)g,
                                     (__attribute__((address_space(3))) u32*)l, 16, 0, 0);
}

// ---------------- fp32 -> bf16 elementwise ----------------
__global__ __launch_bounds__(256) void cvt_bf16_k(const float* __restrict__ x,
                                                  unsigned short* __restrict__ y, int n) {
    int i = (blockIdx.x * 256 + threadIdx.x) * 4;
    if (i < n) {
        float4 v = *(const float4*)(x + i);
        uint2 o;
        o.x = (unsigned int)f2bf(v.x) | ((unsigned int)f2bf(v.y) << 16);
        o.y = (unsigned int)f2bf(v.z) | ((unsigned int)f2bf(v.w) << 16);
        *(uint2*)(y + i) = o;
    }
}

// ---------------- W[K,N] fp32 -> Wt[N,K] bf16 ----------------
__global__ __launch_bounds__(256) void transpose_cvt_k(const float* __restrict__ W,
                                                       unsigned short* __restrict__ Wt,
                                                       int K, int N) {
    __shared__ float tile[32][33];
    int n0 = blockIdx.x * 32, k0 = blockIdx.y * 32;
    int t = threadIdx.x, lr = t >> 5, lc = t & 31;
#pragma unroll
    for (int p = 0; p < 4; p++) {
        int k = k0 + lr + p * 8, n = n0 + lc;
        tile[lr + p * 8][lc] = (k < K && n < N) ? W[(size_t)k * N + n] : 0.f;
    }
    __syncthreads();
#pragma unroll
    for (int p = 0; p < 4; p++) {
        int n = n0 + lr + p * 8, k = k0 + lc;
        if (n < N && k < K) Wt[(size_t)n * K + k] = f2bf(tile[lc][lr + p * 8]);
    }
}

// ---------------- C[M,N] fp32 = A[M,K] bf16 @ Bt[N,K] bf16 ----------------
// 128x128 tile, BK=32, async global_load_lds staging (m97 pattern).
__global__ __launch_bounds__(256) void gemm_bf16_k(const unsigned short* __restrict__ A,
                                                   const unsigned short* __restrict__ Bt,
                                                   float* __restrict__ C,
                                                   int M, int N, int K) {
    __shared__ __align__(16) unsigned short As[128 * 32];
    __shared__ __align__(16) unsigned short Bs[128 * 32];
    int bm = blockIdx.y * 128, bn = blockIdx.x * 128;
    int t = threadIdx.x;
    int wave = t >> 6, lane = t & 63;
    int wr = (wave >> 1) * 64, wc = (wave & 1) * 64;
    int l15 = lane & 15, quad = lane >> 4;
    f32x4 acc[4][4];
    f32x4 zero = {0.f, 0.f, 0.f, 0.f};
#pragma unroll
    for (int i = 0; i < 4; i++)
#pragma unroll
        for (int j = 0; j < 4; j++) acc[i][j] = zero;
    int r0 = 16 * (2 * wave) + (lane >> 2);
    int cOff = (lane & 3) * 8;   // shorts
    const unsigned short* gA0 = A + (size_t)(bm + r0) * K + cOff;
    const unsigned short* gA1 = A + (size_t)(bm + r0 + 16) * K + cOff;
    const unsigned short* gB0 = Bt + (size_t)(bn + r0) * K + cOff;
    const unsigned short* gB1 = Bt + (size_t)(bn + r0 + 16) * K + cOff;
    unsigned short* lA0 = &As[(2 * wave) * 512];
    unsigned short* lA1 = &As[(2 * wave + 1) * 512];
    unsigned short* lB0 = &Bs[(2 * wave) * 512];
    unsigned short* lB1 = &Bs[(2 * wave + 1) * 512];
    for (int k0 = 0; k0 < K; k0 += 32) {
        gload16(gA0 + k0, lA0);
        gload16(gA1 + k0, lA1);
        gload16(gB0 + k0, lB0);
        gload16(gB1 + k0, lB1);
        __syncthreads();   // drains vmcnt: async loads landed
        bf16x8 af[4], bfr[4];
#pragma unroll
        for (int i = 0; i < 4; i++)
            af[i] = *(const bf16x8*)&As[(wr + i * 16 + l15) * 32 + quad * 8];
#pragma unroll
        for (int j = 0; j < 4; j++)
            bfr[j] = *(const bf16x8*)&Bs[(wc + j * 16 + l15) * 32 + quad * 8];
#pragma unroll
        for (int i = 0; i < 4; i++)
#pragma unroll
            for (int j = 0; j < 4; j++)
                acc[i][j] = __builtin_amdgcn_mfma_f32_16x16x32_bf16(af[i], bfr[j], acc[i][j], 0, 0, 0);
        __syncthreads();
    }
#pragma unroll
    for (int i = 0; i < 4; i++) {
        int row = bm + wr + i * 16 + quad * 4;
#pragma unroll
        for (int j = 0; j < 4; j++) {
            int col = bn + wc + j * 16 + l15;
            if (col < N) {
                float* cp = C + (size_t)row * N + col;
#pragma unroll
                for (int r = 0; r < 4; r++) cp[(size_t)r * N] = acc[i][j][r];
            }
        }
    }
}

// ---------------- RMSNorm (block per row) ----------------
__global__ __launch_bounds__(256) void rmsnorm_k(const float* __restrict__ x,
                                                 const float* __restrict__ w,
                                                 unsigned short* __restrict__ y, int cols) {
    int row = blockIdx.x, t = threadIdx.x;
    const float* xr = x + (size_t)row * cols;
    float s = 0.f;
    for (int i = t; i < cols; i += 256) { float v = xr[i]; s += v * v; }
    __shared__ float red[256];
    red[t] = s; __syncthreads();
    for (int o = 128; o > 0; o >>= 1) { if (t < o) red[t] += red[t + o]; __syncthreads(); }
    float scale = rsqrtf(red[0] / (float)cols + 1e-6f);
    unsigned short* yr = y + (size_t)row * cols;
    for (int i = t; i < cols; i += 256) yr[i] = f2bf(xr[i] * scale * w[i]);
}

// ---------------- ckv[T,576] -> rmsnorm(512) bf16 + roped k_pe[64] bf16 ----------------
__global__ __launch_bounds__(256) void kvprep_k(const float* __restrict__ ckv,
                                                const float* __restrict__ w,
                                                const float* __restrict__ cosb,
                                                const float* __restrict__ sinb,
                                                unsigned short* __restrict__ ckvn,
                                                unsigned short* __restrict__ kpe) {
    int row = blockIdx.x, t = threadIdx.x;
    const float* xr = ckv + (size_t)row * 576;
    float s = 0.f;
#pragma unroll
    for (int i = t; i < 512; i += 256) { float v = xr[i]; s += v * v; }
    __shared__ float red[256];
    red[t] = s; __syncthreads();
    for (int o = 128; o > 0; o >>= 1) { if (t < o) red[t] += red[t + o]; __syncthreads(); }
    float scale = rsqrtf(red[0] / 512.f + 1e-6f);
    unsigned short* yr = ckvn + (size_t)row * 512;
#pragma unroll
    for (int i = t; i < 512; i += 256) yr[i] = f2bf(xr[i] * scale * w[i]);
    if (t < 32) {
        float e = xr[512 + 2 * t], o = xr[512 + 2 * t + 1];
        float c = cosb[row * 32 + t], sn = sinb[row * 32 + t];
        kpe[row * 64 + t]      = f2bf(e * c - o * sn);
        kpe[row * 64 + 32 + t] = f2bf(o * c + e * sn);
    }
}

// ---------------- q[T, H*192] fp32 -> Q bf16 with rope, pre-scaled by 192^-0.5 --------
__global__ __launch_bounds__(256) void qprep_k(const float* __restrict__ q,
                                               const float* __restrict__ cosb,
                                               const float* __restrict__ sinb,
                                               unsigned short* __restrict__ Qb) {
    const float SCALE = 0.07216878364870323f; // 192^-0.5 folded into Q
    int trow = blockIdx.x, t = threadIdx.x;
    const float* qr = q + (size_t)trow * (NH * HEADD);
    unsigned short* yr = Qb + (size_t)trow * (NH * HEADD);
    for (int i = t; i < NH * HEADD; i += 256) {
        int h = i / HEADD, d = i - h * HEADD;
        float val;
        if (d < NOPE) val = qr[i];
        else {
            int j = d - NOPE;
            int jj = j & 31;
            const float* pe = qr + h * HEADD + NOPE;
            float e = pe[2 * jj], o = pe[2 * jj + 1];
            float c = cosb[trow * 32 + jj], sn = sinb[trow * 32 + jj];
            val = (j < 32) ? (e * c - o * sn) : (o * c + e * sn);
        }
        yr[i] = f2bf(val * SCALE);
    }
}

// Attention-ready padded tiled layouts (staged whole via global_load_lds):
//   Kb2 [bh][kt=32][64 rows][KS_STRIDE=200]  (25600 B / tile)
//   Vt2 [bh][kt=32][128 dims][VT_STRIDE=72]  (18432 B / tile)
#define KS_STRIDE 200
#define VT_STRIDE 72
#define P_STRIDE  72

// ---------------- kvb[T,4096] fp32 -> Kb2 (k_pe broadcast) ----------------
__global__ __launch_bounds__(256) void kprep_k(const float* __restrict__ kvb,
                                               const unsigned short* __restrict__ kpe,
                                               unsigned short* __restrict__ Kb2) {
    int trow = blockIdx.x, t = threadIdx.x;
    int b = trow >> 11, s = trow & 2047;
    int ktile = s >> 6, srow = s & 63;
    const float* kr = kvb + (size_t)trow * 4096;
    for (int i = t; i < NH * HEADD; i += 256) {
        int h = i / HEADD, d = i - h * HEADD;
        unsigned short v = (d < NOPE) ? f2bf(kr[h * 256 + d]) : kpe[trow * 64 + (d - NOPE)];
        Kb2[(((size_t)(b * NH + h) * 32 + ktile) * 64 + srow) * KS_STRIDE + d] = v;
    }
}

// ---------------- kvb[T,4096] fp32 -> Vt2 (transposed per 64-key tile) ----------
__global__ __launch_bounds__(256) void vtrans_k(const float* __restrict__ kvb,
                                                unsigned short* __restrict__ Vt2) {
    __shared__ unsigned short tile[64][132];
    int st = blockIdx.x, h = blockIdx.y, b = blockIdx.z;
    int t = threadIdx.x;
    int s0 = b * SEQ + st * 64;
    for (int c = t; c < 64 * 32; c += 256) {
        int r = c >> 5, d4 = (c & 31) * 4;
        float4 v = *(const float4*)(kvb + (size_t)(s0 + r) * 4096 + h * 256 + NOPE + d4);
        tile[r][d4]     = f2bf(v.x);
        tile[r][d4 + 1] = f2bf(v.y);
        tile[r][d4 + 2] = f2bf(v.z);
        tile[r][d4 + 3] = f2bf(v.w);
    }
    __syncthreads();
    int bh = b * NH + h;
    for (int c = t; c < 128 * 16; c += 256) {
        int d = c >> 4, s4 = (c & 15) * 4;
        unsigned short p0 = tile[s4][d], p1 = tile[s4 + 1][d];
        unsigned short p2 = tile[s4 + 2][d], p3 = tile[s4 + 3][d];
        uint2 o;
        o.x = (unsigned int)p0 | ((unsigned int)p1 << 16);
        o.y = (unsigned int)p2 | ((unsigned int)p3 << 16);
        *(uint2*)(Vt2 + (((size_t)bh * 32 + st) * 128 + d) * VT_STRIDE + s4) = o;
    }
}

// ---------------- split-K causal flash attention, MFMA bf16 ----------------
// q-tile = 128 rows (8 waves x 16 rows, 512 threads); key chunk = 512 (8 x 64-tiles).
// Per bh: 40 (qt,chunk) blocks, chunk-ascending within qt-ascending; launched
// biggest-qt-first. Each staged K/V tile now serves 128 q-rows (2x reuse vs r4).
// P is wave-private -> no barrier between P-write and PV (lgkmcnt only).
__global__ __launch_bounds__(512) void attn_mfma_k(const unsigned short* __restrict__ Qb,
                                                   const unsigned short* __restrict__ Kb2,
                                                   const unsigned short* __restrict__ Vt2,
                                                   unsigned short* __restrict__ Opart,
                                                   float* __restrict__ Mbuf,
                                                   float* __restrict__ Lbuf) {
    __shared__ __align__(16) unsigned short Ks[64 * KS_STRIDE];    // 25.6 KB
    __shared__ __align__(16) unsigned short Vts[128 * VT_STRIDE];  // 18.4 KB
    __shared__ __align__(16) unsigned short Pw[8 * 16 * P_STRIDE]; // 18.4 KB
    int xe = 39 - blockIdx.x;              // descending: big qt first
    int h  = blockIdx.y;
    int b  = blockIdx.z;
    int qt = 0, accn = 0;                   // decode (qt, chunk): qt group size = qt/4+1
    while (true) { int c = (qt >> 2) + 1; if (xe < accn + c) break; accn += c; qt++; }
    int chunk = xe - accn;
    int t = threadIdx.x;
    int w = t >> 6, lane = t & 63;
    int l15 = lane & 15, quad = lane >> 4;
    int bh = b * NH + h;
    int q0 = b * SEQ + qt * 128;
    int qloc = qt * 128 + w * 16 + quad * 4;
    int flat = bh * 40 + xe;

    // preload Q fragments: wave w owns Q rows q0 + w*16 + (0..15)
    bf16x8 qf[6];
    {
        const unsigned short* qbase = Qb + ((size_t)(q0 + w * 16 + l15) * NH + h) * HEADD + quad * 8;
#pragma unroll
        for (int c = 0; c < 6; c++)
            qf[c] = *(const bf16x8*)(qbase + c * 32);
    }
    f32x4 acc_o[8];
    f32x4 zero = {0.f, 0.f, 0.f, 0.f};
#pragma unroll
    for (int j = 0; j < 8; j++) acc_o[j] = zero;
    float mrun[4], lrun[4];
#pragma unroll
    for (int r = 0; r < 4; r++) { mrun[r] = -1e30f; lrun[r] = 0.f; }

    unsigned short* Pme = Pw + w * 16 * P_STRIDE;
    int kt0 = chunk * 8, kt1 = min(kt0 + 7, 2 * qt + 1);
    int cbeg = w * 5 + min(w, 3), cnt = (w < 3) ? 6 : 5;   // 43 chunks over 8 waves
    for (int kt = kt0; kt <= kt1; kt++) {
        __syncthreads();   // all waves done reading Ks/Vts from prev iter
        {   // async stage K tile (25 x 1KB) + Vt tile (18 x 1KB)
            const unsigned short* kg = Kb2 + ((size_t)bh * 32 + kt) * (64 * KS_STRIDE) + lane * 8;
            const unsigned short* vg = Vt2 + ((size_t)bh * 32 + kt) * (128 * VT_STRIDE) + lane * 8;
            for (int c = cbeg; c < cbeg + cnt; c++) {
                if (c < 25) gload16(kg + c * 512, &Ks[c * 512]);
                else        gload16(vg + (c - 25) * 512, &Vts[(c - 25) * 512]);
            }
        }
        __syncthreads();   // vmcnt drained: tiles resident in LDS
        // S = Q K^T (Q pre-scaled by 192^-0.5 in qprep)
        f32x4 acc_s[4];
#pragma unroll
        for (int j = 0; j < 4; j++) acc_s[j] = zero;
#pragma unroll
        for (int c = 0; c < 6; c++) {
#pragma unroll
            for (int j = 0; j < 4; j++) {
                bf16x8 kf = *(const bf16x8*)&Ks[(j * 16 + l15) * KS_STRIDE + c * 32 + quad * 8];
                acc_s[j] = __builtin_amdgcn_mfma_f32_16x16x32_bf16(qf[c], kf, acc_s[j], 0, 0, 0);
            }
        }
        float sv[4][4];
#pragma unroll
        for (int j = 0; j < 4; j++) {
            int kcol = kt * 64 + j * 16 + l15;
#pragma unroll
            for (int r = 0; r < 4; r++)
                sv[j][r] = (kcol > qloc + r) ? -1e30f : acc_s[j][r];
        }
        float alpha[4];
#pragma unroll
        for (int r = 0; r < 4; r++) {
            float v = fmaxf(fmaxf(sv[0][r], sv[1][r]), fmaxf(sv[2][r], sv[3][r]));
            v = fmaxf(v, __shfl_xor(v, 1));
            v = fmaxf(v, __shfl_xor(v, 2));
            v = fmaxf(v, __shfl_xor(v, 4));
            v = fmaxf(v, __shfl_xor(v, 8));
            float mnew = fmaxf(mrun[r], v);
            alpha[r] = __expf(mrun[r] - mnew);
            mrun[r] = mnew;
            float rs = 0.f;
#pragma unroll
            for (int j = 0; j < 4; j++) { float p = __expf(sv[j][r] - mnew); sv[j][r] = p; rs += p; }
            rs += __shfl_xor(rs, 1);
            rs += __shfl_xor(rs, 2);
            rs += __shfl_xor(rs, 4);
            rs += __shfl_xor(rs, 8);
            lrun[r] = lrun[r] * alpha[r] + rs;
        }
        // P (bf16) to wave-private LDS region; no block barrier needed
#pragma unroll
        for (int j = 0; j < 4; j++)
#pragma unroll
            for (int r = 0; r < 4; r++)
                Pme[(quad * 4 + r) * P_STRIDE + j * 16 + l15] = f2bf(sv[j][r]);
#pragma unroll
        for (int jt = 0; jt < 8; jt++)
#pragma unroll
            for (int r = 0; r < 4; r++) acc_o[jt][r] *= alpha[r];
        // O += P @ V
#pragma unroll
        for (int c2 = 0; c2 < 2; c2++) {
            bf16x8 pf = *(const bf16x8*)&Pme[l15 * P_STRIDE + c2 * 32 + quad * 8];
#pragma unroll
            for (int jt = 0; jt < 8; jt++) {
                bf16x8 vf = *(const bf16x8*)&Vts[(jt * 16 + l15) * VT_STRIDE + c2 * 32 + quad * 8];
                acc_o[jt] = __builtin_amdgcn_mfma_f32_16x16x32_bf16(pf, vf, acc_o[jt], 0, 0, 0);
            }
        }
    }
    // epilogue: unnormalized partial O (bf16, 128x128 tile) + m,l (fp32)
#pragma unroll
    for (int r = 0; r < 4; r++) {
        int row = w * 16 + quad * 4 + r;
        unsigned short* op = Opart + (size_t)flat * 16384 + row * 128 + l15;
#pragma unroll
        for (int jt = 0; jt < 8; jt++)
            op[jt * 16] = f2bf(acc_o[jt][r]);
        if (l15 == 0) {
            Mbuf[(size_t)flat * 128 + row] = mrun[r];
            Lbuf[(size_t)flat * 128 + row] = lrun[r];
        }
    }
}

// ---------------- combine: merge <=4 chunk partials, normalize, write attnb ----------
// Block = 64 q-rows (half of a 128-row Opart tile).
__global__ __launch_bounds__(256) void attn_combine_k(const unsigned short* __restrict__ Opart,
                                                      const float* __restrict__ Mbuf,
                                                      const float* __restrict__ Lbuf,
                                                      unsigned short* __restrict__ attnb) {
    int q64 = blockIdx.x, h = blockIdx.y, b = blockIdx.z;
    int qt = q64 >> 1, half = q64 & 1;
    int nch = (qt >> 2) + 1;
    int F = 0;
    for (int q = 0; q < qt; q++) F += (q >> 2) + 1;
    int flat0 = (b * NH + h) * 40 + F;
    int t = threadIdx.x;
    int row = t >> 2, d0 = (t & 3) * 32;
    int row128 = half * 64 + row;
    float mc[4], lc[4], wgt[4];
    float mstar = -1e30f;
#pragma unroll
    for (int c = 0; c < 4; c++) {
        if (c < nch) {
            mc[c] = Mbuf[(size_t)(flat0 + c) * 128 + row128];
            lc[c] = Lbuf[(size_t)(flat0 + c) * 128 + row128];
        } else { mc[c] = -1e30f; lc[c] = 0.f; }
        mstar = fmaxf(mstar, mc[c]);
    }
    float L = 0.f;
#pragma unroll
    for (int c = 0; c < 4; c++) { wgt[c] = __expf(mc[c] - mstar); L += wgt[c] * lc[c]; }
    float invL = 1.f / L;
    float acc[32];
#pragma unroll
    for (int j = 0; j < 32; j++) acc[j] = 0.f;
#pragma unroll
    for (int c = 0; c < 4; c++) {
        if (c < nch) {
            const unsigned short* src = Opart + (size_t)(flat0 + c) * 16384 + row128 * 128 + d0;
            float wc = wgt[c];
#pragma unroll
            for (int g = 0; g < 4; g++) {
                uint4 u = *(const uint4*)(src + g * 8);
                const unsigned short* sp = (const unsigned short*)&u;
#pragma unroll
                for (int j = 0; j < 8; j++) acc[g * 8 + j] += wc * bf2f(sp[j]);
            }
        }
    }
    unsigned short* dst = attnb + (size_t)(b * SEQ + q64 * 64 + row) * 2048 + h * 128 + d0;
#pragma unroll
    for (int g = 0; g < 4; g++) {
        uint4 o;
        unsigned short* sp = (unsigned short*)&o;
#pragma unroll
        for (int j = 0; j < 8; j++) sp[j] = f2bf(acc[g * 8 + j] * invL);
        *(uint4*)(dst + g * 8) = o;
    }
}

// =====================================================================
extern "C" void kernel_launch(void* const* d_in, const int* in_sizes, int n_in,
                              void* d_out, int out_size, void* d_ws, size_t ws_size,
                              hipStream_t stream) {
    const float* hs     = (const float*)d_in[0];
    const float* cosb   = (const float*)d_in[1];
    const float* sinb   = (const float*)d_in[2];
    const float* w_q_a  = (const float*)d_in[3];
    const float* q_ln   = (const float*)d_in[4];
    const float* w_q_b  = (const float*)d_in[5];
    const float* w_kv_a = (const float*)d_in[6];
    const float* kv_ln  = (const float*)d_in[7];
    const float* w_kv_b = (const float*)d_in[8];
    const float* w_o    = (const float*)d_in[9];
    float* out = (float*)d_out;

    char* base = (char*)d_ws;
    size_t off = 0;
    auto take = [&](size_t bytes) { void* p = base + off; off += (bytes + 255) & ~(size_t)255; return p; };
    unsigned short* wqaT  = (unsigned short*)take((size_t)1536 * 2048 * 2);
    unsigned short* wqbT  = (unsigned short*)take((size_t)3072 * 1536 * 2);
    unsigned short* wkvaT = (unsigned short*)take((size_t)576 * 2048 * 2);
    unsigned short* wkvbT = (unsigned short*)take((size_t)4096 * 512 * 2);
    unsigned short* woT   = (unsigned short*)take((size_t)2048 * 2048 * 2);
    unsigned short* hsb   = (unsigned short*)take((size_t)TT * DD * 2);
    unsigned short* qan   = (unsigned short*)take((size_t)TT * 1536 * 2);
    unsigned short* ckvn  = (unsigned short*)take((size_t)TT * 512 * 2);
    unsigned short* kpe   = (unsigned short*)take((size_t)TT * 64 * 2);
    unsigned short* Qbuf  = (unsigned short*)take((size_t)TT * NH * HEADD * 2);
    unsigned short* Kb2   = (unsigned short*)take((size_t)32 * 32 * 64 * KS_STRIDE * 2);   // 26.2 MB
    unsigned short* Vt2   = (unsigned short*)take((size_t)32 * 32 * 128 * VT_STRIDE * 2);  // 18.9 MB
    unsigned short* attnb = (unsigned short*)take((size_t)TT * 2048 * 2);
    char* Sreg = (char*)take((size_t)TT * 4096 * 4);   // 64 MB multipurpose
    float* S = (float*)Sreg;                            // fp32 GEMM scratch (pre-attention)
    unsigned short* Opart = (unsigned short*)Sreg;                       // 1280*128*128 bf16 = 41.9MB
    float* Mbuf = (float*)(Sreg + (size_t)1280 * 16384 * 2);
    float* Lbuf = Mbuf + (size_t)1280 * 128;

    // 0. activations + weights to bf16 (weights transposed to [N,K])
    cvt_bf16_k<<<(TT * DD) / 1024, 256, 0, stream>>>(hs, hsb, TT * DD);
    transpose_cvt_k<<<dim3(1536 / 32, 2048 / 32), 256, 0, stream>>>(w_q_a, wqaT, 2048, 1536);
    transpose_cvt_k<<<dim3(3072 / 32, 1536 / 32), 256, 0, stream>>>(w_q_b, wqbT, 1536, 3072);
    transpose_cvt_k<<<dim3(18, 2048 / 32), 256, 0, stream>>>(w_kv_a, wkvaT, 2048, 576);
    transpose_cvt_k<<<dim3(4096 / 32, 512 / 32), 256, 0, stream>>>(w_kv_b, wkvbT, 512, 4096);
    transpose_cvt_k<<<dim3(2048 / 32, 2048 / 32), 256, 0, stream>>>(w_o, woT, 2048, 2048);

    // 1. q_a = hs @ w_q_a ; rmsnorm -> qan (bf16)
    gemm_bf16_k<<<dim3(12, 32), 256, 0, stream>>>(hsb, wqaT, S, 4096, 1536, 2048);
    rmsnorm_k<<<4096, 256, 0, stream>>>(S, q_ln, qan, 1536);
    // 2. ckv = hs @ w_kv_a ; rmsnorm(512) + rope(k_pe)
    gemm_bf16_k<<<dim3(5, 32), 256, 0, stream>>>(hsb, wkvaT, S, 4096, 576, 2048);
    kvprep_k<<<4096, 256, 0, stream>>>(S, kv_ln, cosb, sinb, ckvn, kpe);
    // 3. q = qan @ w_q_b ; rope (+ scale fold) -> Qbuf
    gemm_bf16_k<<<dim3(24, 32), 256, 0, stream>>>(qan, wqbT, S, 4096, 3072, 1536);
    qprep_k<<<4096, 256, 0, stream>>>(S, cosb, sinb, Qbuf);
    // 4. kv = ckvn @ w_kv_b ; K -> Kb2 (padded tiled), V -> Vt2 (transposed tiled)
    gemm_bf16_k<<<dim3(32, 32), 256, 0, stream>>>(ckvn, wkvbT, S, 4096, 4096, 512);
    kprep_k<<<4096, 256, 0, stream>>>(S, kpe, Kb2);
    vtrans_k<<<dim3(32, 16, 2), 256, 0, stream>>>(S, Vt2);
    // 5. split-K attention (1280 blocks x 512 thr) + combine
    attn_mfma_k<<<dim3(40, 16, 2), 512, 0, stream>>>(Qbuf, Kb2, Vt2, Opart, Mbuf, Lbuf);
    attn_combine_k<<<dim3(32, 16, 2), 256, 0, stream>>>(Opart, Mbuf, Lbuf, attnb);
    // 6. out = attn @ w_o
    gemm_bf16_k<<<dim3(16, 32), 256, 0, stream>>>(attnb, woT, out, 4096, 2048, 2048);
}

// Round 6
// 554.411 us; speedup vs baseline: 4.5099x; 1.0736x over previous
//
#include <hip/hip_runtime.h>
#include <cstdint>
#include <cstddef>

// Shapes are fixed by setup_inputs(): T=4096, D=2048, B=2, S=2048.
#define TT 4096
#define DD 2048
#define NH 16
#define HEADD 192
#define NOPE 128
#define VDIM 128
#define SEQ 2048

typedef __bf16 bf16x8 __attribute__((ext_vector_type(8)));
typedef float f32x4 __attribute__((ext_vector_type(4)));
typedef unsigned int u32;

__device__ __forceinline__ float bf2f(unsigned short u) {
    union { unsigned int i; float f; } v; v.i = ((unsigned int)u) << 16; return v.f;
}
__device__ __forceinline__ unsigned short f2bf(float f) {
    union { float f; unsigned int i; } v; v.f = f;
    unsigned int r = v.i + 0x7FFFu + ((v.i >> 16) & 1u);
    return (unsigned short)(r >> 16);
}
// async global->LDS, 16B per lane; LDS dest = wave-uniform base + lane*16
__device__ __forceinline__ void gload16(const unsigned short* g, unsigned short* l) {
    __builtin_amdgcn_global_load_lds((const __attribute__((address_space(1))) u32*)g,
                                     (__attribute__((address_space(3))) u32*)l, 16, 0, 0);
}

// ---------------- fp32 -> bf16 elementwise ----------------
__global__ __launch_bounds__(256) void cvt_bf16_k(const float* __restrict__ x,
                                                  unsigned short* __restrict__ y, int n) {
    int i = (blockIdx.x * 256 + threadIdx.x) * 4;
    if (i < n) {
        float4 v = *(const float4*)(x + i);
        uint2 o;
        o.x = (unsigned int)f2bf(v.x) | ((unsigned int)f2bf(v.y) << 16);
        o.y = (unsigned int)f2bf(v.z) | ((unsigned int)f2bf(v.w) << 16);
        *(uint2*)(y + i) = o;
    }
}

// ---------------- W[K,N] fp32 -> Wt[N,K] bf16 ----------------
__global__ __launch_bounds__(256) void transpose_cvt_k(const float* __restrict__ W,
                                                       unsigned short* __restrict__ Wt,
                                                       int K, int N) {
    __shared__ float tile[32][33];
    int n0 = blockIdx.x * 32, k0 = blockIdx.y * 32;
    int t = threadIdx.x, lr = t >> 5, lc = t & 31;
#pragma unroll
    for (int p = 0; p < 4; p++) {
        int k = k0 + lr + p * 8, n = n0 + lc;
        tile[lr + p * 8][lc] = (k < K && n < N) ? W[(size_t)k * N + n] : 0.f;
    }
    __syncthreads();
#pragma unroll
    for (int p = 0; p < 4; p++) {
        int n = n0 + lr + p * 8, k = k0 + lc;
        if (n < N && k < K) Wt[(size_t)n * K + k] = f2bf(tile[lc][lr + p * 8]);
    }
}

// ---------------- C[M,N] fp32 = A[M,K] bf16 @ Bt[N,K] bf16 (m97-style) ------------
__global__ __launch_bounds__(256) void gemm_bf16_k(const unsigned short* __restrict__ A,
                                                   const unsigned short* __restrict__ Bt,
                                                   float* __restrict__ C,
                                                   int M, int N, int K) {
    __shared__ __align__(16) unsigned short As[128 * 32];
    __shared__ __align__(16) unsigned short Bs[128 * 32];
    int bm = blockIdx.y * 128, bn = blockIdx.x * 128;
    int t = threadIdx.x;
    int wave = t >> 6, lane = t & 63;
    int wr = (wave >> 1) * 64, wc = (wave & 1) * 64;
    int l15 = lane & 15, quad = lane >> 4;
    f32x4 acc[4][4];
    f32x4 zero = {0.f, 0.f, 0.f, 0.f};
#pragma unroll
    for (int i = 0; i < 4; i++)
#pragma unroll
        for (int j = 0; j < 4; j++) acc[i][j] = zero;
    int r0 = 16 * (2 * wave) + (lane >> 2);
    int cOff = (lane & 3) * 8;
    const unsigned short* gA0 = A + (size_t)(bm + r0) * K + cOff;
    const unsigned short* gA1 = A + (size_t)(bm + r0 + 16) * K + cOff;
    const unsigned short* gB0 = Bt + (size_t)(bn + r0) * K + cOff;
    const unsigned short* gB1 = Bt + (size_t)(bn + r0 + 16) * K + cOff;
    unsigned short* lA0 = &As[(2 * wave) * 512];
    unsigned short* lA1 = &As[(2 * wave + 1) * 512];
    unsigned short* lB0 = &Bs[(2 * wave) * 512];
    unsigned short* lB1 = &Bs[(2 * wave + 1) * 512];
    for (int k0 = 0; k0 < K; k0 += 32) {
        gload16(gA0 + k0, lA0);
        gload16(gA1 + k0, lA1);
        gload16(gB0 + k0, lB0);
        gload16(gB1 + k0, lB1);
        __syncthreads();
        bf16x8 af[4], bfr[4];
#pragma unroll
        for (int i = 0; i < 4; i++)
            af[i] = *(const bf16x8*)&As[(wr + i * 16 + l15) * 32 + quad * 8];
#pragma unroll
        for (int j = 0; j < 4; j++)
            bfr[j] = *(const bf16x8*)&Bs[(wc + j * 16 + l15) * 32 + quad * 8];
#pragma unroll
        for (int i = 0; i < 4; i++)
#pragma unroll
            for (int j = 0; j < 4; j++)
                acc[i][j] = __builtin_amdgcn_mfma_f32_16x16x32_bf16(af[i], bfr[j], acc[i][j], 0, 0, 0);
        __syncthreads();
    }
#pragma unroll
    for (int i = 0; i < 4; i++) {
        int row = bm + wr + i * 16 + quad * 4;
#pragma unroll
        for (int j = 0; j < 4; j++) {
            int col = bn + wc + j * 16 + l15;
            if (col < N) {
                float* cp = C + (size_t)row * N + col;
#pragma unroll
                for (int r = 0; r < 4; r++) cp[(size_t)r * N] = acc[i][j][r];
            }
        }
    }
}

// ---------------- same GEMM but bf16 output ----------------
__global__ __launch_bounds__(256) void gemm_bf16o_k(const unsigned short* __restrict__ A,
                                                    const unsigned short* __restrict__ Bt,
                                                    unsigned short* __restrict__ C,
                                                    int M, int N, int K) {
    __shared__ __align__(16) unsigned short As[128 * 32];
    __shared__ __align__(16) unsigned short Bs[128 * 32];
    int bm = blockIdx.y * 128, bn = blockIdx.x * 128;
    int t = threadIdx.x;
    int wave = t >> 6, lane = t & 63;
    int wr = (wave >> 1) * 64, wc = (wave & 1) * 64;
    int l15 = lane & 15, quad = lane >> 4;
    f32x4 acc[4][4];
    f32x4 zero = {0.f, 0.f, 0.f, 0.f};
#pragma unroll
    for (int i = 0; i < 4; i++)
#pragma unroll
        for (int j = 0; j < 4; j++) acc[i][j] = zero;
    int r0 = 16 * (2 * wave) + (lane >> 2);
    int cOff = (lane & 3) * 8;
    const unsigned short* gA0 = A + (size_t)(bm + r0) * K + cOff;
    const unsigned short* gA1 = A + (size_t)(bm + r0 + 16) * K + cOff;
    const unsigned short* gB0 = Bt + (size_t)(bn + r0) * K + cOff;
    const unsigned short* gB1 = Bt + (size_t)(bn + r0 + 16) * K + cOff;
    unsigned short* lA0 = &As[(2 * wave) * 512];
    unsigned short* lA1 = &As[(2 * wave + 1) * 512];
    unsigned short* lB0 = &Bs[(2 * wave) * 512];
    unsigned short* lB1 = &Bs[(2 * wave + 1) * 512];
    for (int k0 = 0; k0 < K; k0 += 32) {
        gload16(gA0 + k0, lA0);
        gload16(gA1 + k0, lA1);
        gload16(gB0 + k0, lB0);
        gload16(gB1 + k0, lB1);
        __syncthreads();
        bf16x8 af[4], bfr[4];
#pragma unroll
        for (int i = 0; i < 4; i++)
            af[i] = *(const bf16x8*)&As[(wr + i * 16 + l15) * 32 + quad * 8];
#pragma unroll
        for (int j = 0; j < 4; j++)
            bfr[j] = *(const bf16x8*)&Bs[(wc + j * 16 + l15) * 32 + quad * 8];
#pragma unroll
        for (int i = 0; i < 4; i++)
#pragma unroll
            for (int j = 0; j < 4; j++)
                acc[i][j] = __builtin_amdgcn_mfma_f32_16x16x32_bf16(af[i], bfr[j], acc[i][j], 0, 0, 0);
        __syncthreads();
    }
#pragma unroll
    for (int i = 0; i < 4; i++) {
        int row = bm + wr + i * 16 + quad * 4;
#pragma unroll
        for (int j = 0; j < 4; j++) {
            int col = bn + wc + j * 16 + l15;
            if (col < N) {
                unsigned short* cp = C + (size_t)row * N + col;
#pragma unroll
                for (int r = 0; r < 4; r++) cp[(size_t)r * N] = f2bf(acc[i][j][r]);
            }
        }
    }
}

// Attention-ready padded tiled layouts:
//   Kb2 [bh][kt=32][64 rows][KS_STRIDE=200]
//   Vt2 [bh][kt=32][128 dims][VT_STRIDE=72]
#define KS_STRIDE 200
#define VT_STRIDE 72
#define P_STRIDE  72

// ---------------- kv GEMM with fused K/V-split epilogue --------------------
// kv = ckvn[4096x512] @ wkvbT; output col c: h=c>>8, dd=c&255.
// dd<128 -> Kb2 nope slot; dd>=128 -> Vt2 (transposed) slot. No fp32 round-trip.
__global__ __launch_bounds__(256) void gemm_kv_k(const unsigned short* __restrict__ A,
                                                 const unsigned short* __restrict__ Bt,
                                                 unsigned short* __restrict__ Kb2,
                                                 unsigned short* __restrict__ Vt2) {
    const int K = 512;
    __shared__ __align__(16) unsigned short As[128 * 32];
    __shared__ __align__(16) unsigned short Bs[128 * 32];
    int bm = blockIdx.y * 128, bn = blockIdx.x * 128;
    int t = threadIdx.x;
    int wave = t >> 6, lane = t & 63;
    int wr = (wave >> 1) * 64, wc = (wave & 1) * 64;
    int l15 = lane & 15, quad = lane >> 4;
    f32x4 acc[4][4];
    f32x4 zero = {0.f, 0.f, 0.f, 0.f};
#pragma unroll
    for (int i = 0; i < 4; i++)
#pragma unroll
        for (int j = 0; j < 4; j++) acc[i][j] = zero;
    int r0 = 16 * (2 * wave) + (lane >> 2);
    int cOff = (lane & 3) * 8;
    const unsigned short* gA0 = A + (size_t)(bm + r0) * K + cOff;
    const unsigned short* gA1 = A + (size_t)(bm + r0 + 16) * K + cOff;
    const unsigned short* gB0 = Bt + (size_t)(bn + r0) * K + cOff;
    const unsigned short* gB1 = Bt + (size_t)(bn + r0 + 16) * K + cOff;
    unsigned short* lA0 = &As[(2 * wave) * 512];
    unsigned short* lA1 = &As[(2 * wave + 1) * 512];
    unsigned short* lB0 = &Bs[(2 * wave) * 512];
    unsigned short* lB1 = &Bs[(2 * wave + 1) * 512];
    for (int k0 = 0; k0 < K; k0 += 32) {
        gload16(gA0 + k0, lA0);
        gload16(gA1 + k0, lA1);
        gload16(gB0 + k0, lB0);
        gload16(gB1 + k0, lB1);
        __syncthreads();
        bf16x8 af[4], bfr[4];
#pragma unroll
        for (int i = 0; i < 4; i++)
            af[i] = *(const bf16x8*)&As[(wr + i * 16 + l15) * 32 + quad * 8];
#pragma unroll
        for (int j = 0; j < 4; j++)
            bfr[j] = *(const bf16x8*)&Bs[(wc + j * 16 + l15) * 32 + quad * 8];
#pragma unroll
        for (int i = 0; i < 4; i++)
#pragma unroll
            for (int j = 0; j < 4; j++)
                acc[i][j] = __builtin_amdgcn_mfma_f32_16x16x32_bf16(af[i], bfr[j], acc[i][j], 0, 0, 0);
        __syncthreads();
    }
#pragma unroll
    for (int j = 0; j < 4; j++) {
        int col = bn + wc + j * 16 + l15;
        int h = col >> 8, dd = col & 255;
#pragma unroll
        for (int i = 0; i < 4; i++) {
            int row0 = bm + wr + i * 16 + quad * 4;
#pragma unroll
            for (int r = 0; r < 4; r++) {
                int row = row0 + r;
                int b = row >> 11, s = row & 2047;
                int kt = s >> 6, sr = s & 63;
                size_t bh = (size_t)(b * NH + h);
                unsigned short v = f2bf(acc[i][j][r]);
                if (dd < 128)
                    Kb2[((bh * 32 + kt) * 64 + sr) * KS_STRIDE + dd] = v;
                else
                    Vt2[((bh * 32 + kt) * 128 + (dd - 128)) * VT_STRIDE + sr] = v;
            }
        }
    }
}

// ---------------- broadcast roped k_pe into Kb2 dims [128,192) ----------------
__global__ __launch_bounds__(256) void kpe_fill_k(const unsigned short* __restrict__ kpe,
                                                  unsigned short* __restrict__ Kb2) {
    int trow = blockIdx.x, t = threadIdx.x;
    int b = trow >> 11, s = trow & 2047;
    int kt = s >> 6, sr = s & 63;
    const unsigned short* src = kpe + trow * 64;
#pragma unroll
    for (int i = t; i < NH * 64; i += 256) {
        int h = i >> 6, d = i & 63;
        Kb2[(((size_t)(b * NH + h) * 32 + kt) * 64 + sr) * KS_STRIDE + 128 + d] = src[d];
    }
}

// ---------------- RMSNorm over bf16 input (cols 0..1535 of qab, stride 2112) -------
__global__ __launch_bounds__(256) void rmsnorm_bf_k(const unsigned short* __restrict__ x,
                                                    const float* __restrict__ w,
                                                    unsigned short* __restrict__ y) {
    int row = blockIdx.x, t = threadIdx.x;
    const unsigned short* xr = x + (size_t)row * 2112;
    float s = 0.f;
    for (int i = t; i < 1536; i += 256) { float v = bf2f(xr[i]); s += v * v; }
    __shared__ float red[256];
    red[t] = s; __syncthreads();
    for (int o = 128; o > 0; o >>= 1) { if (t < o) red[t] += red[t + o]; __syncthreads(); }
    float scale = rsqrtf(red[0] / 1536.f + 1e-6f);
    unsigned short* yr = y + (size_t)row * 1536;
    for (int i = t; i < 1536; i += 256) yr[i] = f2bf(bf2f(xr[i]) * scale * w[i]);
}

// ---------------- ckv part of qab (cols 1536..2111): rmsnorm(512) + rope k_pe ------
__global__ __launch_bounds__(256) void kvprep_bf_k(const unsigned short* __restrict__ qab,
                                                   const float* __restrict__ w,
                                                   const float* __restrict__ cosb,
                                                   const float* __restrict__ sinb,
                                                   unsigned short* __restrict__ ckvn,
                                                   unsigned short* __restrict__ kpe) {
    int row = blockIdx.x, t = threadIdx.x;
    const unsigned short* xr = qab + (size_t)row * 2112 + 1536;
    float s = 0.f;
#pragma unroll
    for (int i = t; i < 512; i += 256) { float v = bf2f(xr[i]); s += v * v; }
    __shared__ float red[256];
    red[t] = s; __syncthreads();
    for (int o = 128; o > 0; o >>= 1) { if (t < o) red[t] += red[t + o]; __syncthreads(); }
    float scale = rsqrtf(red[0] / 512.f + 1e-6f);
    unsigned short* yr = ckvn + (size_t)row * 512;
#pragma unroll
    for (int i = t; i < 512; i += 256) yr[i] = f2bf(bf2f(xr[i]) * scale * w[i]);
    if (t < 32) {
        float e = bf2f(xr[512 + 2 * t]), o = bf2f(xr[512 + 2 * t + 1]);
        float c = cosb[row * 32 + t], sn = sinb[row * 32 + t];
        kpe[row * 64 + t]      = f2bf(e * c - o * sn);
        kpe[row * 64 + 32 + t] = f2bf(o * c + e * sn);
    }
}

// ---------------- q bf16 [T,3072] -> Qbuf with rope + 192^-0.5 scale fold ---------
__global__ __launch_bounds__(256) void qprep_bf_k(const unsigned short* __restrict__ q,
                                                  const float* __restrict__ cosb,
                                                  const float* __restrict__ sinb,
                                                  unsigned short* __restrict__ Qb) {
    const float SCALE = 0.07216878364870323f;
    int trow = blockIdx.x, t = threadIdx.x;
    const unsigned short* qr = q + (size_t)trow * (NH * HEADD);
    unsigned short* yr = Qb + (size_t)trow * (NH * HEADD);
    for (int i = t; i < NH * HEADD; i += 256) {
        int h = i / HEADD, d = i - h * HEADD;
        float val;
        if (d < NOPE) val = bf2f(qr[i]);
        else {
            int j = d - NOPE;
            int jj = j & 31;
            const unsigned short* pe = qr + h * HEADD + NOPE;
            float e = bf2f(pe[2 * jj]), o = bf2f(pe[2 * jj + 1]);
            float c = cosb[trow * 32 + jj], sn = sinb[trow * 32 + jj];
            val = (j < 32) ? (e * c - o * sn) : (o * c + e * sn);
        }
        yr[i] = f2bf(val * SCALE);
    }
}

// ---------------- split-K causal flash attention, MFMA bf16 ----------------
__global__ __launch_bounds__(512) void attn_mfma_k(const unsigned short* __restrict__ Qb,
                                                   const unsigned short* __restrict__ Kb2,
                                                   const unsigned short* __restrict__ Vt2,
                                                   unsigned short* __restrict__ Opart,
                                                   float* __restrict__ Mbuf,
                                                   float* __restrict__ Lbuf) {
    __shared__ __align__(16) unsigned short Ks[64 * KS_STRIDE];
    __shared__ __align__(16) unsigned short Vts[128 * VT_STRIDE];
    __shared__ __align__(16) unsigned short Pw[8 * 16 * P_STRIDE];
    int xe = 39 - blockIdx.x;
    int h  = blockIdx.y;
    int b  = blockIdx.z;
    int qt = 0, accn = 0;
    while (true) { int c = (qt >> 2) + 1; if (xe < accn + c) break; accn += c; qt++; }
    int chunk = xe - accn;
    int t = threadIdx.x;
    int w = t >> 6, lane = t & 63;
    int l15 = lane & 15, quad = lane >> 4;
    int bh = b * NH + h;
    int q0 = b * SEQ + qt * 128;
    int qloc = qt * 128 + w * 16 + quad * 4;
    int flat = bh * 40 + xe;

    bf16x8 qf[6];
    {
        const unsigned short* qbase = Qb + ((size_t)(q0 + w * 16 + l15) * NH + h) * HEADD + quad * 8;
#pragma unroll
        for (int c = 0; c < 6; c++)
            qf[c] = *(const bf16x8*)(qbase + c * 32);
    }
    f32x4 acc_o[8];
    f32x4 zero = {0.f, 0.f, 0.f, 0.f};
#pragma unroll
    for (int j = 0; j < 8; j++) acc_o[j] = zero;
    float mrun[4], lrun[4];
#pragma unroll
    for (int r = 0; r < 4; r++) { mrun[r] = -1e30f; lrun[r] = 0.f; }

    unsigned short* Pme = Pw + w * 16 * P_STRIDE;
    int kt0 = chunk * 8, kt1 = min(kt0 + 7, 2 * qt + 1);
    int cbeg = w * 5 + min(w, 3), cnt = (w < 3) ? 6 : 5;
    for (int kt = kt0; kt <= kt1; kt++) {
        __syncthreads();
        {
            const unsigned short* kg = Kb2 + ((size_t)bh * 32 + kt) * (64 * KS_STRIDE) + lane * 8;
            const unsigned short* vg = Vt2 + ((size_t)bh * 32 + kt) * (128 * VT_STRIDE) + lane * 8;
            for (int c = cbeg; c < cbeg + cnt; c++) {
                if (c < 25) gload16(kg + c * 512, &Ks[c * 512]);
                else        gload16(vg + (c - 25) * 512, &Vts[(c - 25) * 512]);
            }
        }
        __syncthreads();
        f32x4 acc_s[4];
#pragma unroll
        for (int j = 0; j < 4; j++) acc_s[j] = zero;
#pragma unroll
        for (int c = 0; c < 6; c++) {
#pragma unroll
            for (int j = 0; j < 4; j++) {
                bf16x8 kf = *(const bf16x8*)&Ks[(j * 16 + l15) * KS_STRIDE + c * 32 + quad * 8];
                acc_s[j] = __builtin_amdgcn_mfma_f32_16x16x32_bf16(qf[c], kf, acc_s[j], 0, 0, 0);
            }
        }
        float sv[4][4];
#pragma unroll
        for (int j = 0; j < 4; j++) {
            int kcol = kt * 64 + j * 16 + l15;
#pragma unroll
            for (int r = 0; r < 4; r++)
                sv[j][r] = (kcol > qloc + r) ? -1e30f : acc_s[j][r];
        }
        float alpha[4];
#pragma unroll
        for (int r = 0; r < 4; r++) {
            float v = fmaxf(fmaxf(sv[0][r], sv[1][r]), fmaxf(sv[2][r], sv[3][r]));
            v = fmaxf(v, __shfl_xor(v, 1));
            v = fmaxf(v, __shfl_xor(v, 2));
            v = fmaxf(v, __shfl_xor(v, 4));
            v = fmaxf(v, __shfl_xor(v, 8));
            float mnew = fmaxf(mrun[r], v);
            alpha[r] = __expf(mrun[r] - mnew);
            mrun[r] = mnew;
            float rs = 0.f;
#pragma unroll
            for (int j = 0; j < 4; j++) { float p = __expf(sv[j][r] - mnew); sv[j][r] = p; rs += p; }
            rs += __shfl_xor(rs, 1);
            rs += __shfl_xor(rs, 2);
            rs += __shfl_xor(rs, 4);
            rs += __shfl_xor(rs, 8);
            lrun[r] = lrun[r] * alpha[r] + rs;
        }
#pragma unroll
        for (int j = 0; j < 4; j++)
#pragma unroll
            for (int r = 0; r < 4; r++)
                Pme[(quad * 4 + r) * P_STRIDE + j * 16 + l15] = f2bf(sv[j][r]);
#pragma unroll
        for (int jt = 0; jt < 8; jt++)
#pragma unroll
            for (int r = 0; r < 4; r++) acc_o[jt][r] *= alpha[r];
#pragma unroll
        for (int c2 = 0; c2 < 2; c2++) {
            bf16x8 pf = *(const bf16x8*)&Pme[l15 * P_STRIDE + c2 * 32 + quad * 8];
#pragma unroll
            for (int jt = 0; jt < 8; jt++) {
                bf16x8 vf = *(const bf16x8*)&Vts[(jt * 16 + l15) * VT_STRIDE + c2 * 32 + quad * 8];
                acc_o[jt] = __builtin_amdgcn_mfma_f32_16x16x32_bf16(pf, vf, acc_o[jt], 0, 0, 0);
            }
        }
    }
#pragma unroll
    for (int r = 0; r < 4; r++) {
        int row = w * 16 + quad * 4 + r;
        unsigned short* op = Opart + (size_t)flat * 16384 + row * 128 + l15;
#pragma unroll
        for (int jt = 0; jt < 8; jt++)
            op[jt * 16] = f2bf(acc_o[jt][r]);
        if (l15 == 0) {
            Mbuf[(size_t)flat * 128 + row] = mrun[r];
            Lbuf[(size_t)flat * 128 + row] = lrun[r];
        }
    }
}

// ---------------- combine: merge <=4 chunk partials, normalize, write attnb ----------
__global__ __launch_bounds__(256) void attn_combine_k(const unsigned short* __restrict__ Opart,
                                                      const float* __restrict__ Mbuf,
                                                      const float* __restrict__ Lbuf,
                                                      unsigned short* __restrict__ attnb) {
    int q64 = blockIdx.x, h = blockIdx.y, b = blockIdx.z;
    int qt = q64 >> 1, half = q64 & 1;
    int nch = (qt >> 2) + 1;
    int F = 0;
    for (int q = 0; q < qt; q++) F += (q >> 2) + 1;
    int flat0 = (b * NH + h) * 40 + F;
    int t = threadIdx.x;
    int row = t >> 2, d0 = (t & 3) * 32;
    int row128 = half * 64 + row;
    float mc[4], lc[4], wgt[4];
    float mstar = -1e30f;
#pragma unroll
    for (int c = 0; c < 4; c++) {
        if (c < nch) {
            mc[c] = Mbuf[(size_t)(flat0 + c) * 128 + row128];
            lc[c] = Lbuf[(size_t)(flat0 + c) * 128 + row128];
        } else { mc[c] = -1e30f; lc[c] = 0.f; }
        mstar = fmaxf(mstar, mc[c]);
    }
    float L = 0.f;
#pragma unroll
    for (int c = 0; c < 4; c++) { wgt[c] = __expf(mc[c] - mstar); L += wgt[c] * lc[c]; }
    float invL = 1.f / L;
    float acc[32];
#pragma unroll
    for (int j = 0; j < 32; j++) acc[j] = 0.f;
#pragma unroll
    for (int c = 0; c < 4; c++) {
        if (c < nch) {
            const unsigned short* src = Opart + (size_t)(flat0 + c) * 16384 + row128 * 128 + d0;
            float wc = wgt[c];
#pragma unroll
            for (int g = 0; g < 4; g++) {
                uint4 u = *(const uint4*)(src + g * 8);
                const unsigned short* sp = (const unsigned short*)&u;
#pragma unroll
                for (int j = 0; j < 8; j++) acc[g * 8 + j] += wc * bf2f(sp[j]);
            }
        }
    }
    unsigned short* dst = attnb + (size_t)(b * SEQ + q64 * 64 + row) * 2048 + h * 128 + d0;
#pragma unroll
    for (int g = 0; g < 4; g++) {
        uint4 o;
        unsigned short* sp = (unsigned short*)&o;
#pragma unroll
        for (int j = 0; j < 8; j++) sp[j] = f2bf(acc[g * 8 + j] * invL);
        *(uint4*)(dst + g * 8) = o;
    }
}

// =====================================================================
extern "C" void kernel_launch(void* const* d_in, const int* in_sizes, int n_in,
                              void* d_out, int out_size, void* d_ws, size_t ws_size,
                              hipStream_t stream) {
    const float* hs     = (const float*)d_in[0];
    const float* cosb   = (const float*)d_in[1];
    const float* sinb   = (const float*)d_in[2];
    const float* w_q_a  = (const float*)d_in[3];
    const float* q_ln   = (const float*)d_in[4];
    const float* w_q_b  = (const float*)d_in[5];
    const float* w_kv_a = (const float*)d_in[6];
    const float* kv_ln  = (const float*)d_in[7];
    const float* w_kv_b = (const float*)d_in[8];
    const float* w_o    = (const float*)d_in[9];
    float* out = (float*)d_out;

    char* base = (char*)d_ws;
    size_t off = 0;
    auto take = [&](size_t bytes) { void* p = base + off; off += (bytes + 255) & ~(size_t)255; return p; };
    unsigned short* wqabT = (unsigned short*)take((size_t)2112 * 2048 * 2);  // w_q_a^T ++ w_kv_a^T
    unsigned short* wqbT  = (unsigned short*)take((size_t)3072 * 1536 * 2);
    unsigned short* wkvbT = (unsigned short*)take((size_t)4096 * 512 * 2);
    unsigned short* woT   = (unsigned short*)take((size_t)2048 * 2048 * 2);
    unsigned short* hsb   = (unsigned short*)take((size_t)TT * DD * 2);
    unsigned short* qab   = (unsigned short*)take((size_t)TT * 2112 * 2);   // [q_a | ckv] bf16
    unsigned short* qan   = (unsigned short*)take((size_t)TT * 1536 * 2);
    unsigned short* ckvn  = (unsigned short*)take((size_t)TT * 512 * 2);
    unsigned short* kpe   = (unsigned short*)take((size_t)TT * 64 * 2);
    unsigned short* qb3   = (unsigned short*)take((size_t)TT * 3072 * 2);   // q bf16 (pre-rope)
    unsigned short* Qbuf  = (unsigned short*)take((size_t)TT * NH * HEADD * 2);
    unsigned short* Kb2   = (unsigned short*)take((size_t)32 * 32 * 64 * KS_STRIDE * 2);
    unsigned short* Vt2   = (unsigned short*)take((size_t)32 * 32 * 128 * VT_STRIDE * 2);
    unsigned short* attnb = (unsigned short*)take((size_t)TT * 2048 * 2);
    unsigned short* Opart = (unsigned short*)take((size_t)1280 * 16384 * 2);
    float* Mbuf = (float*)take((size_t)1280 * 128 * 4);
    float* Lbuf = (float*)take((size_t)1280 * 128 * 4);

    // 0. activations + weights to bf16 (weights transposed to [N,K])
    cvt_bf16_k<<<(TT * DD) / 1024, 256, 0, stream>>>(hs, hsb, TT * DD);
    transpose_cvt_k<<<dim3(1536 / 32, 2048 / 32), 256, 0, stream>>>(w_q_a, wqabT, 2048, 1536);
    transpose_cvt_k<<<dim3(18, 2048 / 32), 256, 0, stream>>>(w_kv_a, wqabT + (size_t)1536 * 2048, 2048, 576);
    transpose_cvt_k<<<dim3(3072 / 32, 1536 / 32), 256, 0, stream>>>(w_q_b, wqbT, 1536, 3072);
    transpose_cvt_k<<<dim3(4096 / 32, 512 / 32), 256, 0, stream>>>(w_kv_b, wkvbT, 512, 4096);
    transpose_cvt_k<<<dim3(2048 / 32, 2048 / 32), 256, 0, stream>>>(w_o, woT, 2048, 2048);

    // 1. [q_a | ckv] = hs @ [w_q_a | w_kv_a]  (one merged GEMM, bf16 out)
    gemm_bf16o_k<<<dim3(17, 32), 256, 0, stream>>>(hsb, wqabT, qab, 4096, 2112, 2048);
    rmsnorm_bf_k<<<4096, 256, 0, stream>>>(qab, q_ln, qan);
    kvprep_bf_k<<<4096, 256, 0, stream>>>(qab, kv_ln, cosb, sinb, ckvn, kpe);
    // 2. q = qan @ w_q_b (bf16 out) ; rope + scale -> Qbuf
    gemm_bf16o_k<<<dim3(24, 32), 256, 0, stream>>>(qan, wqbT, qb3, 4096, 3072, 1536);
    qprep_bf_k<<<4096, 256, 0, stream>>>(qb3, cosb, sinb, Qbuf);
    // 3. kv GEMM with fused split epilogue -> Kb2 (nope) + Vt2 (transposed)
    gemm_kv_k<<<dim3(32, 32), 256, 0, stream>>>(ckvn, wkvbT, Kb2, Vt2);
    kpe_fill_k<<<4096, 256, 0, stream>>>(kpe, Kb2);
    // 4. split-K attention + combine
    attn_mfma_k<<<dim3(40, 16, 2), 512, 0, stream>>>(Qbuf, Kb2, Vt2, Opart, Mbuf, Lbuf);
    attn_combine_k<<<dim3(32, 16, 2), 256, 0, stream>>>(Opart, Mbuf, Lbuf, attnb);
    // 5. out = attn @ w_o (fp32 out)
    gemm_bf16_k<<<dim3(16, 32), 256, 0, stream>>>(attnb, woT, out, 4096, 2048, 2048);
}

// Round 7
// 542.848 us; speedup vs baseline: 4.6060x; 1.0213x over previous
//
#include <hip/hip_runtime.h>
#include <cstdint>
#include <cstddef>

// Shapes are fixed by setup_inputs(): T=4096, D=2048, B=2, S=2048.
#define TT 4096
#define DD 2048
#define NH 16
#define HEADD 192
#define NOPE 128
#define VDIM 128
#define SEQ 2048

typedef __bf16 bf16x8 __attribute__((ext_vector_type(8)));
typedef float f32x4 __attribute__((ext_vector_type(4)));
typedef unsigned int u32;

__device__ __forceinline__ float bf2f(unsigned short u) {
    union { unsigned int i; float f; } v; v.i = ((unsigned int)u) << 16; return v.f;
}
__device__ __forceinline__ unsigned short f2bf(float f) {
    union { float f; unsigned int i; } v; v.f = f;
    unsigned int r = v.i + 0x7FFFu + ((v.i >> 16) & 1u);
    return (unsigned short)(r >> 16);
}
__device__ __forceinline__ u32 pack2bf(float a, float b) {
    return (u32)f2bf(a) | ((u32)f2bf(b) << 16);
}
// async global->LDS, 16B per lane; LDS dest = wave-uniform base + lane*16
__device__ __forceinline__ void gload16(const unsigned short* g, unsigned short* l) {
    __builtin_amdgcn_global_load_lds((const __attribute__((address_space(1))) u32*)g,
                                     (__attribute__((address_space(3))) u32*)l, 16, 0, 0);
}

// ---------------- fp32 -> bf16 elementwise ----------------
__global__ __launch_bounds__(256) void cvt_bf16_k(const float* __restrict__ x,
                                                  unsigned short* __restrict__ y, int n) {
    int i = (blockIdx.x * 256 + threadIdx.x) * 4;
    if (i < n) {
        float4 v = *(const float4*)(x + i);
        uint2 o;
        o.x = pack2bf(v.x, v.y);
        o.y = pack2bf(v.z, v.w);
        *(uint2*)(y + i) = o;
    }
}

// ---------------- W[K,N] fp32 -> Wt[N,K] bf16 ----------------
__global__ __launch_bounds__(256) void transpose_cvt_k(const float* __restrict__ W,
                                                       unsigned short* __restrict__ Wt,
                                                       int K, int N) {
    __shared__ float tile[32][33];
    int n0 = blockIdx.x * 32, k0 = blockIdx.y * 32;
    int t = threadIdx.x, lr = t >> 5, lc = t & 31;
#pragma unroll
    for (int p = 0; p < 4; p++) {
        int k = k0 + lr + p * 8, n = n0 + lc;
        tile[lr + p * 8][lc] = (k < K && n < N) ? W[(size_t)k * N + n] : 0.f;
    }
    __syncthreads();
#pragma unroll
    for (int p = 0; p < 4; p++) {
        int n = n0 + lr + p * 8, k = k0 + lc;
        if (n < N && k < K) Wt[(size_t)n * K + k] = f2bf(tile[lc][lr + p * 8]);
    }
}

// ---------------- C[M,N] fp32 = A[M,K] bf16 @ Bt[N,K] bf16 (m97-style) ------------
__global__ __launch_bounds__(256) void gemm_bf16_k(const unsigned short* __restrict__ A,
                                                   const unsigned short* __restrict__ Bt,
                                                   float* __restrict__ C,
                                                   int M, int N, int K) {
    __shared__ __align__(16) unsigned short As[128 * 32];
    __shared__ __align__(16) unsigned short Bs[128 * 32];
    int bm = blockIdx.y * 128, bn = blockIdx.x * 128;
    int t = threadIdx.x;
    int wave = t >> 6, lane = t & 63;
    int wr = (wave >> 1) * 64, wc = (wave & 1) * 64;
    int l15 = lane & 15, quad = lane >> 4;
    f32x4 acc[4][4];
    f32x4 zero = {0.f, 0.f, 0.f, 0.f};
#pragma unroll
    for (int i = 0; i < 4; i++)
#pragma unroll
        for (int j = 0; j < 4; j++) acc[i][j] = zero;
    int r0 = 16 * (2 * wave) + (lane >> 2);
    int cOff = (lane & 3) * 8;
    const unsigned short* gA0 = A + (size_t)(bm + r0) * K + cOff;
    const unsigned short* gA1 = A + (size_t)(bm + r0 + 16) * K + cOff;
    const unsigned short* gB0 = Bt + (size_t)(bn + r0) * K + cOff;
    const unsigned short* gB1 = Bt + (size_t)(bn + r0 + 16) * K + cOff;
    unsigned short* lA0 = &As[(2 * wave) * 512];
    unsigned short* lA1 = &As[(2 * wave + 1) * 512];
    unsigned short* lB0 = &Bs[(2 * wave) * 512];
    unsigned short* lB1 = &Bs[(2 * wave + 1) * 512];
    for (int k0 = 0; k0 < K; k0 += 32) {
        gload16(gA0 + k0, lA0);
        gload16(gA1 + k0, lA1);
        gload16(gB0 + k0, lB0);
        gload16(gB1 + k0, lB1);
        __syncthreads();
        bf16x8 af[4], bfr[4];
#pragma unroll
        for (int i = 0; i < 4; i++)
            af[i] = *(const bf16x8*)&As[(wr + i * 16 + l15) * 32 + quad * 8];
#pragma unroll
        for (int j = 0; j < 4; j++)
            bfr[j] = *(const bf16x8*)&Bs[(wc + j * 16 + l15) * 32 + quad * 8];
#pragma unroll
        for (int i = 0; i < 4; i++)
#pragma unroll
            for (int j = 0; j < 4; j++)
                acc[i][j] = __builtin_amdgcn_mfma_f32_16x16x32_bf16(af[i], bfr[j], acc[i][j], 0, 0, 0);
        __syncthreads();
    }
#pragma unroll
    for (int i = 0; i < 4; i++) {
        int row = bm + wr + i * 16 + quad * 4;
#pragma unroll
        for (int j = 0; j < 4; j++) {
            int col = bn + wc + j * 16 + l15;
            if (col < N) {
                float* cp = C + (size_t)row * N + col;
#pragma unroll
                for (int r = 0; r < 4; r++) cp[(size_t)r * N] = acc[i][j][r];
            }
        }
    }
}

// ---------------- same GEMM but bf16 output ----------------
__global__ __launch_bounds__(256) void gemm_bf16o_k(const unsigned short* __restrict__ A,
                                                    const unsigned short* __restrict__ Bt,
                                                    unsigned short* __restrict__ C,
                                                    int M, int N, int K) {
    __shared__ __align__(16) unsigned short As[128 * 32];
    __shared__ __align__(16) unsigned short Bs[128 * 32];
    int bm = blockIdx.y * 128, bn = blockIdx.x * 128;
    int t = threadIdx.x;
    int wave = t >> 6, lane = t & 63;
    int wr = (wave >> 1) * 64, wc = (wave & 1) * 64;
    int l15 = lane & 15, quad = lane >> 4;
    f32x4 acc[4][4];
    f32x4 zero = {0.f, 0.f, 0.f, 0.f};
#pragma unroll
    for (int i = 0; i < 4; i++)
#pragma unroll
        for (int j = 0; j < 4; j++) acc[i][j] = zero;
    int r0 = 16 * (2 * wave) + (lane >> 2);
    int cOff = (lane & 3) * 8;
    const unsigned short* gA0 = A + (size_t)(bm + r0) * K + cOff;
    const unsigned short* gA1 = A + (size_t)(bm + r0 + 16) * K + cOff;
    const unsigned short* gB0 = Bt + (size_t)(bn + r0) * K + cOff;
    const unsigned short* gB1 = Bt + (size_t)(bn + r0 + 16) * K + cOff;
    unsigned short* lA0 = &As[(2 * wave) * 512];
    unsigned short* lA1 = &As[(2 * wave + 1) * 512];
    unsigned short* lB0 = &Bs[(2 * wave) * 512];
    unsigned short* lB1 = &Bs[(2 * wave + 1) * 512];
    for (int k0 = 0; k0 < K; k0 += 32) {
        gload16(gA0 + k0, lA0);
        gload16(gA1 + k0, lA1);
        gload16(gB0 + k0, lB0);
        gload16(gB1 + k0, lB1);
        __syncthreads();
        bf16x8 af[4], bfr[4];
#pragma unroll
        for (int i = 0; i < 4; i++)
            af[i] = *(const bf16x8*)&As[(wr + i * 16 + l15) * 32 + quad * 8];
#pragma unroll
        for (int j = 0; j < 4; j++)
            bfr[j] = *(const bf16x8*)&Bs[(wc + j * 16 + l15) * 32 + quad * 8];
#pragma unroll
        for (int i = 0; i < 4; i++)
#pragma unroll
            for (int j = 0; j < 4; j++)
                acc[i][j] = __builtin_amdgcn_mfma_f32_16x16x32_bf16(af[i], bfr[j], acc[i][j], 0, 0, 0);
        __syncthreads();
    }
#pragma unroll
    for (int i = 0; i < 4; i++) {
        int row = bm + wr + i * 16 + quad * 4;
#pragma unroll
        for (int j = 0; j < 4; j++) {
            int col = bn + wc + j * 16 + l15;
            if (col < N) {
                unsigned short* cp = C + (size_t)row * N + col;
#pragma unroll
                for (int r = 0; r < 4; r++) cp[(size_t)r * N] = f2bf(acc[i][j][r]);
            }
        }
    }
}

// Attention-ready padded tiled layouts:
//   Kb2 [bh][kt=32][64 rows][KS_STRIDE=200]
//   Vt2 [bh][kt=32][128 dims][VT_STRIDE=72]
#define KS_STRIDE 200
#define VT_STRIDE 72

// ---------------- kv GEMM with fused K/V-split epilogue --------------------
__global__ __launch_bounds__(256) void gemm_kv_k(const unsigned short* __restrict__ A,
                                                 const unsigned short* __restrict__ Bt,
                                                 unsigned short* __restrict__ Kb2,
                                                 unsigned short* __restrict__ Vt2) {
    const int K = 512;
    __shared__ __align__(16) unsigned short As[128 * 32];
    __shared__ __align__(16) unsigned short Bs[128 * 32];
    int bm = blockIdx.y * 128, bn = blockIdx.x * 128;
    int t = threadIdx.x;
    int wave = t >> 6, lane = t & 63;
    int wr = (wave >> 1) * 64, wc = (wave & 1) * 64;
    int l15 = lane & 15, quad = lane >> 4;
    f32x4 acc[4][4];
    f32x4 zero = {0.f, 0.f, 0.f, 0.f};
#pragma unroll
    for (int i = 0; i < 4; i++)
#pragma unroll
        for (int j = 0; j < 4; j++) acc[i][j] = zero;
    int r0 = 16 * (2 * wave) + (lane >> 2);
    int cOff = (lane & 3) * 8;
    const unsigned short* gA0 = A + (size_t)(bm + r0) * K + cOff;
    const unsigned short* gA1 = A + (size_t)(bm + r0 + 16) * K + cOff;
    const unsigned short* gB0 = Bt + (size_t)(bn + r0) * K + cOff;
    const unsigned short* gB1 = Bt + (size_t)(bn + r0 + 16) * K + cOff;
    unsigned short* lA0 = &As[(2 * wave) * 512];
    unsigned short* lA1 = &As[(2 * wave + 1) * 512];
    unsigned short* lB0 = &Bs[(2 * wave) * 512];
    unsigned short* lB1 = &Bs[(2 * wave + 1) * 512];
    for (int k0 = 0; k0 < K; k0 += 32) {
        gload16(gA0 + k0, lA0);
        gload16(gA1 + k0, lA1);
        gload16(gB0 + k0, lB0);
        gload16(gB1 + k0, lB1);
        __syncthreads();
        bf16x8 af[4], bfr[4];
#pragma unroll
        for (int i = 0; i < 4; i++)
            af[i] = *(const bf16x8*)&As[(wr + i * 16 + l15) * 32 + quad * 8];
#pragma unroll
        for (int j = 0; j < 4; j++)
            bfr[j] = *(const bf16x8*)&Bs[(wc + j * 16 + l15) * 32 + quad * 8];
#pragma unroll
        for (int i = 0; i < 4; i++)
#pragma unroll
            for (int j = 0; j < 4; j++)
                acc[i][j] = __builtin_amdgcn_mfma_f32_16x16x32_bf16(af[i], bfr[j], acc[i][j], 0, 0, 0);
        __syncthreads();
    }
#pragma unroll
    for (int j = 0; j < 4; j++) {
        int col = bn + wc + j * 16 + l15;
        int h = col >> 8, dd = col & 255;
#pragma unroll
        for (int i = 0; i < 4; i++) {
            int row0 = bm + wr + i * 16 + quad * 4;
#pragma unroll
            for (int r = 0; r < 4; r++) {
                int row = row0 + r;
                int b = row >> 11, s = row & 2047;
                int kt = s >> 6, sr = s & 63;
                size_t bh = (size_t)(b * NH + h);
                unsigned short v = f2bf(acc[i][j][r]);
                if (dd < 128)
                    Kb2[((bh * 32 + kt) * 64 + sr) * KS_STRIDE + dd] = v;
                else
                    Vt2[((bh * 32 + kt) * 128 + (dd - 128)) * VT_STRIDE + sr] = v;
            }
        }
    }
}

// ---------------- broadcast roped k_pe into Kb2 dims [128,192) ----------------
__global__ __launch_bounds__(256) void kpe_fill_k(const unsigned short* __restrict__ kpe,
                                                  unsigned short* __restrict__ Kb2) {
    int trow = blockIdx.x, t = threadIdx.x;
    int b = trow >> 11, s = trow & 2047;
    int kt = s >> 6, sr = s & 63;
    const unsigned short* src = kpe + trow * 64;
#pragma unroll
    for (int i = t; i < NH * 64; i += 256) {
        int h = i >> 6, d = i & 63;
        Kb2[(((size_t)(b * NH + h) * 32 + kt) * 64 + sr) * KS_STRIDE + 128 + d] = src[d];
    }
}

// ---------------- RMSNorm over bf16 input (cols 0..1535 of qab, stride 2112) -------
__global__ __launch_bounds__(256) void rmsnorm_bf_k(const unsigned short* __restrict__ x,
                                                    const float* __restrict__ w,
                                                    unsigned short* __restrict__ y) {
    int row = blockIdx.x, t = threadIdx.x;
    const unsigned short* xr = x + (size_t)row * 2112;
    float s = 0.f;
    for (int i = t; i < 1536; i += 256) { float v = bf2f(xr[i]); s += v * v; }
    __shared__ float red[256];
    red[t] = s; __syncthreads();
    for (int o = 128; o > 0; o >>= 1) { if (t < o) red[t] += red[t + o]; __syncthreads(); }
    float scale = rsqrtf(red[0] / 1536.f + 1e-6f);
    unsigned short* yr = y + (size_t)row * 1536;
    for (int i = t; i < 1536; i += 256) yr[i] = f2bf(bf2f(xr[i]) * scale * w[i]);
}

// ---------------- ckv part of qab (cols 1536..2111): rmsnorm(512) + rope k_pe ------
__global__ __launch_bounds__(256) void kvprep_bf_k(const unsigned short* __restrict__ qab,
                                                   const float* __restrict__ w,
                                                   const float* __restrict__ cosb,
                                                   const float* __restrict__ sinb,
                                                   unsigned short* __restrict__ ckvn,
                                                   unsigned short* __restrict__ kpe) {
    int row = blockIdx.x, t = threadIdx.x;
    const unsigned short* xr = qab + (size_t)row * 2112 + 1536;
    float s = 0.f;
#pragma unroll
    for (int i = t; i < 512; i += 256) { float v = bf2f(xr[i]); s += v * v; }
    __shared__ float red[256];
    red[t] = s; __syncthreads();
    for (int o = 128; o > 0; o >>= 1) { if (t < o) red[t] += red[t + o]; __syncthreads(); }
    float scale = rsqrtf(red[0] / 512.f + 1e-6f);
    unsigned short* yr = ckvn + (size_t)row * 512;
#pragma unroll
    for (int i = t; i < 512; i += 256) yr[i] = f2bf(bf2f(xr[i]) * scale * w[i]);
    if (t < 32) {
        float e = bf2f(xr[512 + 2 * t]), o = bf2f(xr[512 + 2 * t + 1]);
        float c = cosb[row * 32 + t], sn = sinb[row * 32 + t];
        kpe[row * 64 + t]      = f2bf(e * c - o * sn);
        kpe[row * 64 + 32 + t] = f2bf(o * c + e * sn);
    }
}

// ---------------- q bf16 [T,3072] -> Qbuf with rope + 192^-0.5 scale fold ---------
__global__ __launch_bounds__(256) void qprep_bf_k(const unsigned short* __restrict__ q,
                                                  const float* __restrict__ cosb,
                                                  const float* __restrict__ sinb,
                                                  unsigned short* __restrict__ Qb) {
    const float SCALE = 0.07216878364870323f;
    int trow = blockIdx.x, t = threadIdx.x;
    const unsigned short* qr = q + (size_t)trow * (NH * HEADD);
    unsigned short* yr = Qb + (size_t)trow * (NH * HEADD);
    for (int i = t; i < NH * HEADD; i += 256) {
        int h = i / HEADD, d = i - h * HEADD;
        float val;
        if (d < NOPE) val = bf2f(qr[i]);
        else {
            int j = d - NOPE;
            int jj = j & 31;
            const unsigned short* pe = qr + h * HEADD + NOPE;
            float e = bf2f(pe[2 * jj]), o = bf2f(pe[2 * jj + 1]);
            float c = cosb[trow * 32 + jj], sn = sinb[trow * 32 + jj];
            val = (j < 32) ? (e * c - o * sn) : (o * c + e * sn);
        }
        yr[i] = f2bf(val * SCALE);
    }
}

// ---------------- split-K causal flash attention, MFMA bf16, S^T form ----------------
// Computes S^T = K Q^T (operands swapped; A/B frags have identical lane maps),
// so softmax stats are per-lane scalars (q = lane&15) and P reaches PV as a
// B-fragment via in-register shuffles -- no P LDS buffer. LDS = 44 KB -> 3 blk/CU.
__global__ __launch_bounds__(512) void attn_mfma_k(const unsigned short* __restrict__ Qb,
                                                   const unsigned short* __restrict__ Kb2,
                                                   const unsigned short* __restrict__ Vt2,
                                                   unsigned short* __restrict__ Opart,
                                                   float* __restrict__ Mbuf,
                                                   float* __restrict__ Lbuf) {
    __shared__ __align__(16) unsigned short Ks[64 * KS_STRIDE];    // 25.6 KB
    __shared__ __align__(16) unsigned short Vts[128 * VT_STRIDE];  // 18.4 KB
    int xe = 39 - blockIdx.x;
    int h  = blockIdx.y;
    int b  = blockIdx.z;
    int qt = 0, accn = 0;
    while (true) { int c = (qt >> 2) + 1; if (xe < accn + c) break; accn += c; qt++; }
    int chunk = xe - accn;
    int t = threadIdx.x;
    int w = t >> 6, lane = t & 63;
    int l15 = lane & 15, quad = lane >> 4;
    int bh = b * NH + h;
    int q0 = b * SEQ + qt * 128;
    int qglob = qt * 128 + w * 16 + l15;   // this lane's q-row (local seq index)
    int flat = bh * 40 + xe;

    // Q fragment (B-operand now; same lane map as before): rows q0 + w*16 + l15
    bf16x8 qf[6];
    {
        const unsigned short* qbase = Qb + ((size_t)(q0 + w * 16 + l15) * NH + h) * HEADD + quad * 8;
#pragma unroll
        for (int c = 0; c < 6; c++)
            qf[c] = *(const bf16x8*)(qbase + c * 32);
    }
    f32x4 acc_o[8];                        // O^T: [dim-tile jt][reg r] ; col = q (l15)
    f32x4 zero = {0.f, 0.f, 0.f, 0.f};
#pragma unroll
    for (int j = 0; j < 8; j++) acc_o[j] = zero;
    float mrun = -1e30f, lrun = 0.f;       // per-lane scalars (q-row = l15)

    int kt0 = chunk * 8, kt1 = min(kt0 + 7, 2 * qt + 1);
    int cbeg = w * 5 + min(w, 3), cnt = (w < 3) ? 6 : 5;   // 43 1KB chunks over 8 waves
    for (int kt = kt0; kt <= kt1; kt++) {
        __syncthreads();   // all waves done reading Ks/Vts from prev iter
        {
            const unsigned short* kg = Kb2 + ((size_t)bh * 32 + kt) * (64 * KS_STRIDE) + lane * 8;
            const unsigned short* vg = Vt2 + ((size_t)bh * 32 + kt) * (128 * VT_STRIDE) + lane * 8;
            for (int c = cbeg; c < cbeg + cnt; c++) {
                if (c < 25) gload16(kg + c * 512, &Ks[c * 512]);
                else        gload16(vg + (c - 25) * 512, &Vts[(c - 25) * 512]);
            }
        }
        __syncthreads();   // vmcnt drained: tiles resident in LDS
        // S^T = K Q^T : tile j holds keys j*16.., cols = q
        f32x4 acc_s[4];
#pragma unroll
        for (int j = 0; j < 4; j++) acc_s[j] = zero;
#pragma unroll
        for (int c = 0; c < 6; c++) {
#pragma unroll
            for (int j = 0; j < 4; j++) {
                bf16x8 kf = *(const bf16x8*)&Ks[(j * 16 + l15) * KS_STRIDE + c * 32 + quad * 8];
                acc_s[j] = __builtin_amdgcn_mfma_f32_16x16x32_bf16(kf, qf[c], acc_s[j], 0, 0, 0);
            }
        }
        // mask: lane's element (j,r) is S[q=qglob][key = kt*64 + j*16 + quad*4 + r]
        float sv[4][4];
#pragma unroll
        for (int j = 0; j < 4; j++) {
            int kbase = kt * 64 + j * 16 + quad * 4;
#pragma unroll
            for (int r = 0; r < 4; r++)
                sv[j][r] = (kbase + r > qglob) ? -1e30f : acc_s[j][r];
        }
        // online softmax (per-lane scalar stats; reduce over quads sharing l15)
        float v = sv[0][0];
#pragma unroll
        for (int j = 0; j < 4; j++)
#pragma unroll
            for (int r = 0; r < 4; r++) v = fmaxf(v, sv[j][r]);
        v = fmaxf(v, __shfl_xor(v, 16));
        v = fmaxf(v, __shfl_xor(v, 32));
        float mnew = fmaxf(mrun, v);
        float alpha = __expf(mrun - mnew);
        mrun = mnew;
        float rs = 0.f;
#pragma unroll
        for (int j = 0; j < 4; j++)
#pragma unroll
            for (int r = 0; r < 4; r++) { float p = __expf(sv[j][r] - mnew); sv[j][r] = p; rs += p; }
        rs += __shfl_xor(rs, 16);
        rs += __shfl_xor(rs, 32);
        lrun = lrun * alpha + rs;
        // pack P^T tiles to bf16 dwords: pk[j][d] = keys j*16+quad*4+{2d,2d+1}
        u32 pk[4][2];
#pragma unroll
        for (int j = 0; j < 4; j++) {
            pk[j][0] = pack2bf(sv[j][0], sv[j][1]);
            pk[j][1] = pack2bf(sv[j][2], sv[j][3]);
        }
        // rescale O^T by alpha (per-lane scalar)
#pragma unroll
        for (int jt = 0; jt < 8; jt++)
#pragma unroll
            for (int r = 0; r < 4; r++) acc_o[jt][r] *= alpha;
        // O^T += V^T P^T : build P B-frag via shuffles. For key chunk c2 (32 keys):
        // B[n=l15][k=quad*8+jj] = P[q=l15][key=c2*32+quad*8+jj]; source lane
        // ((2*quad+bit)&3)*16+l15, tile j' = 2*c2 + (quad>>1), regs by jj&3.
        int laneA = (((2 * quad) & 3) << 4) + l15;
        int laneB = (((2 * quad + 1) & 3) << 4) + l15;
        bool hi = (quad & 2) != 0;
#pragma unroll
        for (int c2 = 0; c2 < 2; c2++) {
            u32 a0 = __shfl(pk[2 * c2][0], laneA),     a1 = __shfl(pk[2 * c2][1], laneA);
            u32 b0 = __shfl(pk[2 * c2 + 1][0], laneA), b1 = __shfl(pk[2 * c2 + 1][1], laneA);
            u32 a2 = __shfl(pk[2 * c2][0], laneB),     a3 = __shfl(pk[2 * c2][1], laneB);
            u32 b2 = __shfl(pk[2 * c2 + 1][0], laneB), b3 = __shfl(pk[2 * c2 + 1][1], laneB);
            union { u32 d[4]; bf16x8 v8; } pf;
            pf.d[0] = hi ? b0 : a0;
            pf.d[1] = hi ? b1 : a1;
            pf.d[2] = hi ? b2 : a2;
            pf.d[3] = hi ? b3 : a3;
#pragma unroll
            for (int jt = 0; jt < 8; jt++) {
                bf16x8 vf = *(const bf16x8*)&Vts[(jt * 16 + l15) * VT_STRIDE + c2 * 32 + quad * 8];
                acc_o[jt] = __builtin_amdgcn_mfma_f32_16x16x32_bf16(vf, pf.v8, acc_o[jt], 0, 0, 0);
            }
        }
    }
    // epilogue: O^T lane holds [dim = jt*16+quad*4+r][q = w*16+l15]
    {
        int row = w * 16 + l15;
        unsigned short* op = Opart + (size_t)flat * 16384 + row * 128;
#pragma unroll
        for (int jt = 0; jt < 8; jt++)
#pragma unroll
            for (int r = 0; r < 4; r++)
                op[jt * 16 + quad * 4 + r] = f2bf(acc_o[jt][r]);
        if (quad == 0) {
            Mbuf[(size_t)flat * 128 + row] = mrun;
            Lbuf[(size_t)flat * 128 + row] = lrun;
        }
    }
}

// ---------------- combine: merge <=4 chunk partials, normalize, write attnb ----------
__global__ __launch_bounds__(256) void attn_combine_k(const unsigned short* __restrict__ Opart,
                                                      const float* __restrict__ Mbuf,
                                                      const float* __restrict__ Lbuf,
                                                      unsigned short* __restrict__ attnb) {
    int q64 = blockIdx.x, h = blockIdx.y, b = blockIdx.z;
    int qt = q64 >> 1, half = q64 & 1;
    int nch = (qt >> 2) + 1;
    int F = 0;
    for (int q = 0; q < qt; q++) F += (q >> 2) + 1;
    int flat0 = (b * NH + h) * 40 + F;
    int t = threadIdx.x;
    int row = t >> 2, d0 = (t & 3) * 32;
    int row128 = half * 64 + row;
    float mc[4], lc[4], wgt[4];
    float mstar = -1e30f;
#pragma unroll
    for (int c = 0; c < 4; c++) {
        if (c < nch) {
            mc[c] = Mbuf[(size_t)(flat0 + c) * 128 + row128];
            lc[c] = Lbuf[(size_t)(flat0 + c) * 128 + row128];
        } else { mc[c] = -1e30f; lc[c] = 0.f; }
        mstar = fmaxf(mstar, mc[c]);
    }
    float L = 0.f;
#pragma unroll
    for (int c = 0; c < 4; c++) { wgt[c] = __expf(mc[c] - mstar); L += wgt[c] * lc[c]; }
    float invL = 1.f / L;
    float acc[32];
#pragma unroll
    for (int j = 0; j < 32; j++) acc[j] = 0.f;
#pragma unroll
    for (int c = 0; c < 4; c++) {
        if (c < nch) {
            const unsigned short* src = Opart + (size_t)(flat0 + c) * 16384 + row128 * 128 + d0;
            float wc = wgt[c];
#pragma unroll
            for (int g = 0; g < 4; g++) {
                uint4 u = *(const uint4*)(src + g * 8);
                const unsigned short* sp = (const unsigned short*)&u;
#pragma unroll
                for (int j = 0; j < 8; j++) acc[g * 8 + j] += wc * bf2f(sp[j]);
            }
        }
    }
    unsigned short* dst = attnb + (size_t)(b * SEQ + q64 * 64 + row) * 2048 + h * 128 + d0;
#pragma unroll
    for (int g = 0; g < 4; g++) {
        uint4 o;
        unsigned short* sp = (unsigned short*)&o;
#pragma unroll
        for (int j = 0; j < 8; j++) sp[j] = f2bf(acc[g * 8 + j] * invL);
        *(uint4*)(dst + g * 8) = o;
    }
}

// =====================================================================
extern "C" void kernel_launch(void* const* d_in, const int* in_sizes, int n_in,
                              void* d_out, int out_size, void* d_ws, size_t ws_size,
                              hipStream_t stream) {
    const float* hs     = (const float*)d_in[0];
    const float* cosb   = (const float*)d_in[1];
    const float* sinb   = (const float*)d_in[2];
    const float* w_q_a  = (const float*)d_in[3];
    const float* q_ln   = (const float*)d_in[4];
    const float* w_q_b  = (const float*)d_in[5];
    const float* w_kv_a = (const float*)d_in[6];
    const float* kv_ln  = (const float*)d_in[7];
    const float* w_kv_b = (const float*)d_in[8];
    const float* w_o    = (const float*)d_in[9];
    float* out = (float*)d_out;

    char* base = (char*)d_ws;
    size_t off = 0;
    auto take = [&](size_t bytes) { void* p = base + off; off += (bytes + 255) & ~(size_t)255; return p; };
    unsigned short* wqabT = (unsigned short*)take((size_t)2112 * 2048 * 2);  // w_q_a^T ++ w_kv_a^T
    unsigned short* wqbT  = (unsigned short*)take((size_t)3072 * 1536 * 2);
    unsigned short* wkvbT = (unsigned short*)take((size_t)4096 * 512 * 2);
    unsigned short* woT   = (unsigned short*)take((size_t)2048 * 2048 * 2);
    unsigned short* hsb   = (unsigned short*)take((size_t)TT * DD * 2);
    unsigned short* qab   = (unsigned short*)take((size_t)TT * 2112 * 2);   // [q_a | ckv] bf16
    unsigned short* qan   = (unsigned short*)take((size_t)TT * 1536 * 2);
    unsigned short* ckvn  = (unsigned short*)take((size_t)TT * 512 * 2);
    unsigned short* kpe   = (unsigned short*)take((size_t)TT * 64 * 2);
    unsigned short* qb3   = (unsigned short*)take((size_t)TT * 3072 * 2);   // q bf16 (pre-rope)
    unsigned short* Qbuf  = (unsigned short*)take((size_t)TT * NH * HEADD * 2);
    unsigned short* Kb2   = (unsigned short*)take((size_t)32 * 32 * 64 * KS_STRIDE * 2);
    unsigned short* Vt2   = (unsigned short*)take((size_t)32 * 32 * 128 * VT_STRIDE * 2);
    unsigned short* attnb = (unsigned short*)take((size_t)TT * 2048 * 2);
    unsigned short* Opart = (unsigned short*)take((size_t)1280 * 16384 * 2);
    float* Mbuf = (float*)take((size_t)1280 * 128 * 4);
    float* Lbuf = (float*)take((size_t)1280 * 128 * 4);

    // 0. activations + weights to bf16 (weights transposed to [N,K])
    cvt_bf16_k<<<(TT * DD) / 1024, 256, 0, stream>>>(hs, hsb, TT * DD);
    transpose_cvt_k<<<dim3(1536 / 32, 2048 / 32), 256, 0, stream>>>(w_q_a, wqabT, 2048, 1536);
    transpose_cvt_k<<<dim3(18, 2048 / 32), 256, 0, stream>>>(w_kv_a, wqabT + (size_t)1536 * 2048, 2048, 576);
    transpose_cvt_k<<<dim3(3072 / 32, 1536 / 32), 256, 0, stream>>>(w_q_b, wqbT, 1536, 3072);
    transpose_cvt_k<<<dim3(4096 / 32, 512 / 32), 256, 0, stream>>>(w_kv_b, wkvbT, 512, 4096);
    transpose_cvt_k<<<dim3(2048 / 32, 2048 / 32), 256, 0, stream>>>(w_o, woT, 2048, 2048);

    // 1. [q_a | ckv] = hs @ [w_q_a | w_kv_a]  (one merged GEMM, bf16 out)
    gemm_bf16o_k<<<dim3(17, 32), 256, 0, stream>>>(hsb, wqabT, qab, 4096, 2112, 2048);
    rmsnorm_bf_k<<<4096, 256, 0, stream>>>(qab, q_ln, qan);
    kvprep_bf_k<<<4096, 256, 0, stream>>>(qab, kv_ln, cosb, sinb, ckvn, kpe);
    // 2. q = qan @ w_q_b (bf16 out) ; rope + scale -> Qbuf
    gemm_bf16o_k<<<dim3(24, 32), 256, 0, stream>>>(qan, wqbT, qb3, 4096, 3072, 1536);
    qprep_bf_k<<<4096, 256, 0, stream>>>(qb3, cosb, sinb, Qbuf);
    // 3. kv GEMM with fused split epilogue -> Kb2 (nope) + Vt2 (transposed)
    gemm_kv_k<<<dim3(32, 32), 256, 0, stream>>>(ckvn, wkvbT, Kb2, Vt2);
    kpe_fill_k<<<4096, 256, 0, stream>>>(kpe, Kb2);
    // 4. split-K attention + combine
    attn_mfma_k<<<dim3(40, 16, 2), 512, 0, stream>>>(Qbuf, Kb2, Vt2, Opart, Mbuf, Lbuf);
    attn_combine_k<<<dim3(32, 16, 2), 256, 0, stream>>>(Opart, Mbuf, Lbuf, attnb);
    // 5. out = attn @ w_o (fp32 out)
    gemm_bf16_k<<<dim3(16, 32), 256, 0, stream>>>(attnb, woT, out, 4096, 2048, 2048);
}